// Round 1
// baseline (531.391 us; speedup 1.0000x reference)
//
#include <hip/hip_runtime.h>
#include <hip/hip_bf16.h>

#define B_ 32
#define T_ 256
#define D_ 64
#define H_ 128
#define G_ 384   // 3*H

typedef __hip_bfloat16 bf16;

__device__ __forceinline__ float ldsel(const void* p, int i, int bf) {
  if (bf) return __bfloat162float(((const bf16*)p)[i]);
  return ((const float*)p)[i];
}
__device__ __forceinline__ float fsigmoid(float x){ return 1.0f/(1.0f+__expf(-x)); }
__device__ __forceinline__ float ftanh_(float x){ return 1.0f - 2.0f/(1.0f+__expf(2.0f*x)); }

// flag=1 -> inputs are bf16; flag=0 -> f32.
// missing_mask is exactly {0.0,1.0} in f32; read as u32->f32 over the bf16-sized
// prefix: if ANY value is outside {0,1} the buffer must be bf16-packed.
__global__ void __launch_bounds__(256) detect_k(const unsigned* words, int n, int* flag){
  int bad = 0;
  for (int i = blockIdx.x*blockDim.x + threadIdx.x; i < n; i += gridDim.x*blockDim.x){
    float f = __uint_as_float(words[i]);
    bad |= !(f == 0.0f || f == 1.0f);   // NaN also flags bad
  }
  if (bad) atomicOr(flag, 1);
}

__global__ void __launch_bounds__(256) convert_k(
    const void* x, const void* mm, const void* vt,
    const void* E, const void* wih, const void* whh,
    const void* bih, const void* bhh, const int* flag,
    float* xo, float* vtf, float* Ef, float* wihf, float* whhf,
    float* bihf, float* bhhf){
  int bf = *flag;
  int stride = gridDim.x*blockDim.x;
  int t0 = blockIdx.x*blockDim.x + threadIdx.x;
  for (int i = t0; i < B_*T_*D_; i += stride)
    xo[i] = ldsel(x,i,bf) * (1.0f - ldsel(mm,i,bf));   // x * observed
  for (int i = t0; i < B_*T_; i += stride) vtf[i] = ldsel(vt,i,bf);
  for (int i = t0; i < D_*H_; i += stride) Ef[i]  = ldsel(E,i,bf);
  for (int i = t0; i < G_*H_; i += stride) wihf[i] = ldsel(wih,i,bf);
  for (int i = t0; i < G_*H_; i += stride) whhf[i] = ldsel(whh,i,bf);
  for (int i = t0; i < G_;    i += stride) bihf[i] = ldsel(bih,i,bf);
  for (int i = t0; i < G_;    i += stride) bhhf[i] = ldsel(bhh,i,bf);
}

// Per-batch graph weights: wcol[b,j] = sum_i adj[b,i,j] of the row-normalized adjacency.
// adj_raw[i,j] = p_i p_j sim_ij + I; rowsum_i = 1 + p_i * sum_j p_j sim_ij;
// wcol_j = p_j * sum_i p_i sim_ij / rs_i + 1/rs_j   (sim symmetric).
__global__ void __launch_bounds__(256) adj_k(const void* mm, const int* flag,
                                             const float* Ef, float* wcol){
  int b = blockIdx.x;
  int tid = threadIdx.x;
  int d = tid & 63, q = tid >> 6;          // 64 sensors x 4 slices
  int bf = *flag;
  __shared__ float spp[4][64];
  __shared__ float sp[64];
  __shared__ float sE[64*129];             // pitch 129: breaks the 128-stride bank alias
  __shared__ float ssim[64*65];            // pitch 65
  __shared__ float srs[64];
  float p = 0.0f;
  if (bf){
    const bf16* m = (const bf16*)mm;
    for (int t = q*64; t < q*64+64; t++) p += 1.0f - __bfloat162float(m[(b*T_ + t)*D_ + d]);
  } else {
    const float* m = (const float*)mm;
    for (int t = q*64; t < q*64+64; t++) p += 1.0f - m[(b*T_ + t)*D_ + d];
  }
  spp[q][d] = p;
  for (int i = tid; i < D_*H_; i += 256){ int r = i >> 7, c = i & 127; sE[r*129+c] = Ef[i]; }
  __syncthreads();
  if (tid < 64) sp[tid] = (spp[0][tid]+spp[1][tid]+spp[2][tid]+spp[3][tid]) * (1.0f/T_);
  __syncthreads();
  float rowE[128];
  #pragma unroll
  for (int k = 0; k < 128; k++) rowE[k] = sE[d*129+k];
  for (int i = q*16; i < q*16+16; i++){
    float s = 0.0f;
    #pragma unroll
    for (int k = 0; k < 128; k++) s += rowE[k]*sE[i*129+k];   // broadcast reads
    ssim[d*65+i] = fmaxf(s, 0.0f);
  }
  __syncthreads();
  if (tid < 64){
    float rs = 0.0f;
    for (int j = 0; j < 64; j++) rs += sp[j]*ssim[tid*65+j];
    srs[tid] = fmaxf(sp[tid]*rs + 1.0f, 1e-6f);
  }
  __syncthreads();
  if (tid < 64){
    float s = 0.0f;
    for (int i = 0; i < 64; i++) s += sp[i]*ssim[tid*65+i]/srs[i];
    wcol[b*64 + tid] = sp[tid]*s + 1.0f/srs[tid];
  }
}

// visit_repr + time encoding + input-side GRU GEMM, fused.
// gi[b,t,g] = b_ih[g] + dot128(vr[b,t,:], W_ih[g,:]),
// vr[b,t,h] = (1/64)*dot64(w[b,:]*xo[b,t,:], E[:,h]) + enc(t,h)
__global__ void __launch_bounds__(384) gi_k(const float* xo, const float* vtf,
                                            const float* Ef, const float* wihf,
                                            const float* bihf, const float* wcol,
                                            float* gi){
  int bid = blockIdx.x;            // 256 = 32 b x 8 chunks of 32 t
  int b = bid >> 3, t0 = (bid & 7)*32;
  int tid = threadIdx.x;
  __shared__ float sE[D_*H_];      // lanes read consecutive h -> 2-way (free)
  __shared__ float sv[32*D_];
  __shared__ float svr[32*H_];
  __shared__ float sw[D_];
  for (int i = tid; i < D_*H_; i += 384) sE[i] = Ef[i];
  if (tid < D_) sw[tid] = wcol[b*D_ + tid];
  __syncthreads();
  for (int i = tid; i < 32*D_; i += 384){
    int r = i >> 6, j = i & 63;
    sv[i] = xo[(b*T_ + t0 + r)*D_ + j] * sw[j];
  }
  __syncthreads();
  // phase 1: vr into LDS
  int h = tid & 127, rg = tid >> 7;       // rg in 0..2
  float fr = __expf(-(float)(h & 63) * 0.14391157f);   // ln(1e4)/64
  for (int r = rg; r < 32; r += 3){
    float acc = 0.0f;
    #pragma unroll
    for (int j = 0; j < D_; j++) acc += sv[r*D_+j] * sE[j*H_+h];
    float ang = vtf[b*T_ + t0 + r] * fr;
    float e = (h < 64) ? __sinf(ang) : __cosf(ang);
    svr[r*H_+h] = acc * (1.0f/D_) + e;
  }
  __syncthreads();
  // phase 2: gi = vr @ W_ih^T + b_ih ; W_ih row in 128 VGPRs
  float wr[H_];
  #pragma unroll
  for (int k = 0; k < H_; k += 4){
    float4 v = *(const float4*)&wihf[tid*H_ + k];
    wr[k]=v.x; wr[k+1]=v.y; wr[k+2]=v.z; wr[k+3]=v.w;
  }
  float bi = bihf[tid];
  long base = (long)(b*T_ + t0)*G_;
  for (int r = 0; r < 32; r++){
    float a0=0,a1=0,a2=0,a3=0;
    #pragma unroll
    for (int k = 0; k < H_; k += 4){
      float4 hv = *(const float4*)&svr[r*H_ + k];    // broadcast
      a0 += wr[k]*hv.x; a1 += wr[k+1]*hv.y; a2 += wr[k+2]*hv.z; a3 += wr[k+3]*hv.w;
    }
    gi[base + (long)r*G_ + tid] = bi + ((a0+a1)+(a2+a3));
  }
}

// Sequential GRU: one block per batch element, thread j owns gate-row j.
__global__ void __launch_bounds__(384) gru_k(const float* gi, const float* whhf,
                                             const float* bhhf, const int* lengths,
                                             const int* flag, void* out){
  int b = blockIdx.x;
  int j = threadIdx.x;
  int bf = *flag;
  float wr[H_];
  #pragma unroll
  for (int k = 0; k < H_; k += 4){
    float4 v = *(const float4*)&whhf[j*H_ + k];
    wr[k]=v.x; wr[k+1]=v.y; wr[k+2]=v.z; wr[k+3]=v.w;
  }
  float bh = bhhf[j];
  int len = lengths[b];
  __shared__ float hs[H_];
  __shared__ float gh[G_];
  __shared__ float gis[G_];
  if (j < H_) hs[j] = 0.0f;
  __syncthreads();
  const float* gib = gi + (long)b*T_*G_;
  for (int t = 0; t < T_; t++){
    float giv = gib[(long)t*G_ + j];       // issued early, consumed after dot
    float a0=0,a1=0,a2=0,a3=0;
    #pragma unroll
    for (int k = 0; k < H_; k += 4){
      float4 hv = *(const float4*)&hs[k];  // broadcast
      a0 += wr[k]*hv.x; a1 += wr[k+1]*hv.y; a2 += wr[k+2]*hv.z; a3 += wr[k+3]*hv.w;
    }
    gh[j]  = bh + ((a0+a1)+(a2+a3));
    gis[j] = giv;
    __syncthreads();
    if (j < H_){
      float r = fsigmoid(gis[j]      + gh[j]);
      float z = fsigmoid(gis[H_+j]   + gh[H_+j]);
      float n = ftanh_(gis[2*H_+j] + r*gh[2*H_+j]);
      float hn = (1.0f - z)*n + z*hs[j];
      hs[j] = hn;
      float oval = (t < len) ? hn : 0.0f;
      long oi = (long)(b*T_ + t)*H_ + j;
      if (bf) ((bf16*)out)[oi] = __float2bfloat16(oval);
      else    ((float*)out)[oi] = oval;
    }
    __syncthreads();
  }
}

extern "C" void kernel_launch(void* const* d_in, const int* in_sizes, int n_in,
                              void* d_out, int out_size, void* d_ws, size_t ws_size,
                              hipStream_t stream) {
  char* base = (char*)d_ws;
  size_t off = 0;
  auto alloc = [&](size_t bytes)->void*{
    void* p = base + off; off = (off + bytes + 255) & ~(size_t)255; return p;
  };
  int*   flag = (int*)  alloc(4);
  float* xo   = (float*)alloc((size_t)B_*T_*D_*4);
  float* vtf  = (float*)alloc((size_t)B_*T_*4);
  float* Ef   = (float*)alloc((size_t)D_*H_*4);
  float* wihf = (float*)alloc((size_t)G_*H_*4);
  float* whhf = (float*)alloc((size_t)G_*H_*4);
  float* bihf = (float*)alloc((size_t)G_*4);
  float* bhhf = (float*)alloc((size_t)G_*4);
  float* wcol = (float*)alloc((size_t)B_*D_*4);
  float* gi   = (float*)alloc((size_t)B_*T_*G_*4);
  if (off > ws_size) return;   // workspace too small: fail cleanly (visible as absmax=ref)

  hipMemsetAsync(flag, 0, 4, stream);
  detect_k<<<dim3(256),dim3(256),0,stream>>>((const unsigned*)d_in[1], (B_*T_*D_)/2, flag);
  convert_k<<<dim3(256),dim3(256),0,stream>>>(d_in[0], d_in[1], d_in[2], d_in[5],
                                              d_in[6], d_in[7], d_in[8], d_in[9],
                                              flag, xo, vtf, Ef, wihf, whhf, bihf, bhhf);
  adj_k<<<dim3(B_),dim3(256),0,stream>>>(d_in[1], flag, Ef, wcol);
  gi_k<<<dim3(256),dim3(384),0,stream>>>(xo, vtf, Ef, wihf, bihf, wcol, gi);
  gru_k<<<dim3(B_),dim3(384),0,stream>>>(gi, whhf, bhhf, (const int*)d_in[4], flag, d_out);
}

// Round 2
// 351.897 us; speedup vs baseline: 1.5101x; 1.5101x over previous
//
#include <hip/hip_runtime.h>
#include <hip/hip_bf16.h>

#define B_ 32
#define T_ 256
#define D_ 64
#define H_ 128
#define G_ 384   // 3*H

typedef __hip_bfloat16 bf16;
typedef _Float16 half8 __attribute__((ext_vector_type(8)));
typedef float float4v __attribute__((ext_vector_type(4)));

__device__ __forceinline__ float ldsel(const void* p, int i, int bf) {
  if (bf) return __bfloat162float(((const bf16*)p)[i]);
  return ((const float*)p)[i];
}
__device__ __forceinline__ float fsigmoid(float x){ return 1.0f/(1.0f+__expf(-x)); }
__device__ __forceinline__ float ftanh_(float x){ return 1.0f - 2.0f/(1.0f+__expf(2.0f*x)); }

// flag=1 -> inputs are bf16; flag=0 -> f32 (missing_mask in f32 is exactly {0,1}).
__global__ void __launch_bounds__(256) detect_k(const unsigned* words, int n, int* flag){
  int bad = 0;
  for (int i = blockIdx.x*blockDim.x + threadIdx.x; i < n; i += gridDim.x*blockDim.x){
    float f = __uint_as_float(words[i]);
    bad |= !(f == 0.0f || f == 1.0f);
  }
  if (bad) atomicOr(flag, 1);
}

__global__ void __launch_bounds__(256) convert_k(
    const void* x, const void* mm, const void* vt,
    const void* E, const void* wih, const void* whh,
    const void* bih, const void* bhh, const int* flag,
    float* xo, float* vtf, float* Ef, float* wihf, float* whhf,
    float* bihf, float* bhhf){
  int bf = *flag;
  int stride = gridDim.x*blockDim.x;
  int t0 = blockIdx.x*blockDim.x + threadIdx.x;
  for (int i = t0; i < B_*T_*D_; i += stride)
    xo[i] = ldsel(x,i,bf) * (1.0f - ldsel(mm,i,bf));   // x * observed
  for (int i = t0; i < B_*T_; i += stride) vtf[i] = ldsel(vt,i,bf);
  for (int i = t0; i < D_*H_; i += stride) Ef[i]  = ldsel(E,i,bf);
  for (int i = t0; i < G_*H_; i += stride) wihf[i] = ldsel(wih,i,bf);
  for (int i = t0; i < G_*H_; i += stride) whhf[i] = ldsel(whh,i,bf);
  for (int i = t0; i < G_;    i += stride) bihf[i] = ldsel(bih,i,bf);
  for (int i = t0; i < G_;    i += stride) bhhf[i] = ldsel(bhh,i,bf);
}

// wcol[b,j] = column sums of the row-normalized adjacency (see R1 derivation).
__global__ void __launch_bounds__(256) adj_k(const void* mm, const int* flag,
                                             const float* Ef, float* wcol){
  int b = blockIdx.x;
  int tid = threadIdx.x;
  int d = tid & 63, q = tid >> 6;
  int bf = *flag;
  __shared__ float spp[4][64];
  __shared__ float sp[64];
  __shared__ float sE[64*129];
  __shared__ float ssim[64*65];
  __shared__ float srs[64];
  float p = 0.0f;
  if (bf){
    const bf16* m = (const bf16*)mm;
    for (int t = q*64; t < q*64+64; t++) p += 1.0f - __bfloat162float(m[(b*T_ + t)*D_ + d]);
  } else {
    const float* m = (const float*)mm;
    for (int t = q*64; t < q*64+64; t++) p += 1.0f - m[(b*T_ + t)*D_ + d];
  }
  spp[q][d] = p;
  for (int i = tid; i < D_*H_; i += 256){ int r = i >> 7, c = i & 127; sE[r*129+c] = Ef[i]; }
  __syncthreads();
  if (tid < 64) sp[tid] = (spp[0][tid]+spp[1][tid]+spp[2][tid]+spp[3][tid]) * (1.0f/T_);
  __syncthreads();
  float rowE[128];
  #pragma unroll
  for (int k = 0; k < 128; k++) rowE[k] = sE[d*129+k];
  for (int i = q*16; i < q*16+16; i++){
    float s = 0.0f;
    #pragma unroll
    for (int k = 0; k < 128; k++) s += rowE[k]*sE[i*129+k];
    ssim[d*65+i] = fmaxf(s, 0.0f);
  }
  __syncthreads();
  if (tid < 64){
    float rs = 0.0f;
    for (int j = 0; j < 64; j++) rs += sp[j]*ssim[tid*65+j];
    srs[tid] = fmaxf(sp[tid]*rs + 1.0f, 1e-6f);
  }
  __syncthreads();
  if (tid < 64){
    float s = 0.0f;
    for (int i = 0; i < 64; i++) s += sp[i]*ssim[tid*65+i]/srs[i];
    wcol[b*64 + tid] = sp[tid]*s + 1.0f/srs[tid];
  }
}

// visit_repr + time encoding + input-side GRU GEMM, fused (unchanged from R1).
__global__ void __launch_bounds__(384) gi_k(const float* xo, const float* vtf,
                                            const float* Ef, const float* wihf,
                                            const float* bihf, const float* wcol,
                                            float* gi){
  int bid = blockIdx.x;
  int b = bid >> 3, t0 = (bid & 7)*32;
  int tid = threadIdx.x;
  __shared__ float sE[D_*H_];
  __shared__ float sv[32*D_];
  __shared__ float svr[32*H_];
  __shared__ float sw[D_];
  for (int i = tid; i < D_*H_; i += 384) sE[i] = Ef[i];
  if (tid < D_) sw[tid] = wcol[b*D_ + tid];
  __syncthreads();
  for (int i = tid; i < 32*D_; i += 384){
    int r = i >> 6, j = i & 63;
    sv[i] = xo[(b*T_ + t0 + r)*D_ + j] * sw[j];
  }
  __syncthreads();
  int h = tid & 127, rg = tid >> 7;
  float fr = __expf(-(float)(h & 63) * 0.14391157f);   // ln(1e4)/64
  for (int r = rg; r < 32; r += 3){
    float acc = 0.0f;
    #pragma unroll
    for (int j = 0; j < D_; j++) acc += sv[r*D_+j] * sE[j*H_+h];
    float ang = vtf[b*T_ + t0 + r] * fr;
    float e = (h < 64) ? __sinf(ang) : __cosf(ang);
    svr[r*H_+h] = acc * (1.0f/D_) + e;
  }
  __syncthreads();
  float wr[H_];
  #pragma unroll
  for (int k = 0; k < H_; k += 4){
    float4 v = *(const float4*)&wihf[tid*H_ + k];
    wr[k]=v.x; wr[k+1]=v.y; wr[k+2]=v.z; wr[k+3]=v.w;
  }
  float bi = bihf[tid];
  long base = (long)(b*T_ + t0)*G_;
  for (int r = 0; r < 32; r++){
    float a0=0,a1=0,a2=0,a3=0;
    #pragma unroll
    for (int k = 0; k < H_; k += 4){
      float4 hv = *(const float4*)&svr[r*H_ + k];
      a0 += wr[k]*hv.x; a1 += wr[k+1]*hv.y; a2 += wr[k+2]*hv.z; a3 += wr[k+3]*hv.w;
    }
    gi[base + (long)r*G_ + tid] = bi + ((a0+a1)+(a2+a3));
  }
}

// Sequential GRU, MFMA edition. One block (6 waves) per batch element.
// Wave w owns gh rows [64w, 64w+64): 4 N-tiles of 16, W_hh resident as f16
// B-frags (64 VGPRs). h lives as f16 in LDS (A-frags, identical across the 16
// M-rows so D rows are all equal -> lane l extracts gh[64w+l] directly).
// h itself is carried in f32 registers by threads j<128, so f16 error enters
// only through the gh dot (~5e-4/step, non-compounding).
__global__ void __launch_bounds__(384,1) gru_k(const float* gi, const float* whhf,
                                               const float* bhhf, const int* lengths,
                                               const int* flag, void* out){
  int b = blockIdx.x;
  int tid = threadIdx.x;
  int w = tid >> 6, l = tid & 63;
  int lq = l >> 4, lm = l & 15;
  int bf = *flag;
  int len = lengths[b];

  __shared__ __align__(16) _Float16 hsh[H_];
  __shared__ float gh[G_];

  // Resident B-frags: bfrag[i][kc], B[k][n] = W_hh[64w+16i+n][k]
  // lane holds k = kc*32 + lq*8 + j, n = lm  -> 8 consecutive f32 of one W row.
  half8 bfrag[4][4];
  #pragma unroll
  for (int i = 0; i < 4; i++){
    int row = 64*w + 16*i + lm;
    #pragma unroll
    for (int kc = 0; kc < 4; kc++){
      const float* src = &whhf[row*H_ + kc*32 + lq*8];
      float4 x0 = *(const float4*)src;
      float4 x1 = *(const float4*)(src+4);
      half8 f;
      f[0]=(_Float16)x0.x; f[1]=(_Float16)x0.y; f[2]=(_Float16)x0.z; f[3]=(_Float16)x0.w;
      f[4]=(_Float16)x1.x; f[5]=(_Float16)x1.y; f[6]=(_Float16)x1.z; f[7]=(_Float16)x1.w;
      bfrag[i][kc] = f;
    }
  }
  float bh = bhhf[tid];          // bias for the gh row this thread writes

  const float* gib = gi + (long)b*T_*G_;
  float h = 0.0f;                // thread j<128 carries h[j] in f32
  float p_r=0, p_z=0, p_n=0;     // gi prefetch regs
  if (tid < H_){
    hsh[tid] = (_Float16)0.0f;
    p_r = gib[tid];
    p_z = gib[H_ + tid];
    p_n = gib[2*H_ + tid];
  }
  __syncthreads();

  for (int t = 0; t < T_; t++){
    // --- gh = W_hh * h via MFMA (all 6 waves) ---
    half8 a0 = *(const half8*)&hsh[0*32 + lq*8];
    half8 a1 = *(const half8*)&hsh[1*32 + lq*8];
    half8 a2 = *(const half8*)&hsh[2*32 + lq*8];
    half8 a3 = *(const half8*)&hsh[3*32 + lq*8];
    float4v c0 = {0,0,0,0}, c1 = {0,0,0,0}, c2 = {0,0,0,0}, c3 = {0,0,0,0};
    c0 = __builtin_amdgcn_mfma_f32_16x16x32_f16(a0, bfrag[0][0], c0, 0,0,0);
    c1 = __builtin_amdgcn_mfma_f32_16x16x32_f16(a0, bfrag[1][0], c1, 0,0,0);
    c2 = __builtin_amdgcn_mfma_f32_16x16x32_f16(a0, bfrag[2][0], c2, 0,0,0);
    c3 = __builtin_amdgcn_mfma_f32_16x16x32_f16(a0, bfrag[3][0], c3, 0,0,0);
    c0 = __builtin_amdgcn_mfma_f32_16x16x32_f16(a1, bfrag[0][1], c0, 0,0,0);
    c1 = __builtin_amdgcn_mfma_f32_16x16x32_f16(a1, bfrag[1][1], c1, 0,0,0);
    c2 = __builtin_amdgcn_mfma_f32_16x16x32_f16(a1, bfrag[2][1], c2, 0,0,0);
    c3 = __builtin_amdgcn_mfma_f32_16x16x32_f16(a1, bfrag[3][1], c3, 0,0,0);
    c0 = __builtin_amdgcn_mfma_f32_16x16x32_f16(a2, bfrag[0][2], c0, 0,0,0);
    c1 = __builtin_amdgcn_mfma_f32_16x16x32_f16(a2, bfrag[1][2], c1, 0,0,0);
    c2 = __builtin_amdgcn_mfma_f32_16x16x32_f16(a2, bfrag[2][2], c2, 0,0,0);
    c3 = __builtin_amdgcn_mfma_f32_16x16x32_f16(a2, bfrag[3][2], c3, 0,0,0);
    c0 = __builtin_amdgcn_mfma_f32_16x16x32_f16(a3, bfrag[0][3], c0, 0,0,0);
    c1 = __builtin_amdgcn_mfma_f32_16x16x32_f16(a3, bfrag[1][3], c1, 0,0,0);
    c2 = __builtin_amdgcn_mfma_f32_16x16x32_f16(a3, bfrag[2][3], c2, 0,0,0);
    c3 = __builtin_amdgcn_mfma_f32_16x16x32_f16(a3, bfrag[3][3], c3, 0,0,0);
    // every D row identical -> lane l has gh[64w + 16*lq + lm] = gh[64w+l]
    float v = (lq==0) ? c0[0] : (lq==1) ? c1[0] : (lq==2) ? c2[0] : c3[0];
    gh[tid] = v + bh;

    // gi for this step is already in p_* ; consume and prefetch t+1
    float gir = p_r, giz = p_z, gin = p_n;
    if (tid < H_){
      int tn = (t+1 < T_) ? t+1 : t;
      long bp = (long)tn*G_;
      p_r = gib[bp + tid];
      p_z = gib[bp + H_ + tid];
      p_n = gib[bp + 2*H_ + tid];
    }
    __syncthreads();   // gh visible

    if (tid < H_){
      float r = fsigmoid(gir + gh[tid]);
      float z = fsigmoid(giz + gh[H_ + tid]);
      float n = ftanh_(gin + r*gh[2*H_ + tid]);
      h = (1.0f - z)*n + z*h;
      hsh[tid] = (_Float16)h;
      float oval = (t < len) ? h : 0.0f;
      long oi = (long)(b*T_ + t)*H_ + tid;
      if (bf) ((bf16*)out)[oi] = __float2bfloat16(oval);
      else    ((float*)out)[oi] = oval;
    }
    __syncthreads();   // hsh visible for next step's A-frags
  }
}

extern "C" void kernel_launch(void* const* d_in, const int* in_sizes, int n_in,
                              void* d_out, int out_size, void* d_ws, size_t ws_size,
                              hipStream_t stream) {
  char* base = (char*)d_ws;
  size_t off = 0;
  auto alloc = [&](size_t bytes)->void*{
    void* p = base + off; off = (off + bytes + 255) & ~(size_t)255; return p;
  };
  int*   flag = (int*)  alloc(4);
  float* xo   = (float*)alloc((size_t)B_*T_*D_*4);
  float* vtf  = (float*)alloc((size_t)B_*T_*4);
  float* Ef   = (float*)alloc((size_t)D_*H_*4);
  float* wihf = (float*)alloc((size_t)G_*H_*4);
  float* whhf = (float*)alloc((size_t)G_*H_*4);
  float* bihf = (float*)alloc((size_t)G_*4);
  float* bhhf = (float*)alloc((size_t)G_*4);
  float* wcol = (float*)alloc((size_t)B_*D_*4);
  float* gi   = (float*)alloc((size_t)B_*T_*G_*4);
  if (off > ws_size) return;

  hipMemsetAsync(flag, 0, 4, stream);
  detect_k<<<dim3(256),dim3(256),0,stream>>>((const unsigned*)d_in[1], (B_*T_*D_)/2, flag);
  convert_k<<<dim3(256),dim3(256),0,stream>>>(d_in[0], d_in[1], d_in[2], d_in[5],
                                              d_in[6], d_in[7], d_in[8], d_in[9],
                                              flag, xo, vtf, Ef, wihf, whhf, bihf, bhhf);
  adj_k<<<dim3(B_),dim3(256),0,stream>>>(d_in[1], flag, Ef, wcol);
  gi_k<<<dim3(256),dim3(384),0,stream>>>(xo, vtf, Ef, wihf, bihf, wcol, gi);
  gru_k<<<dim3(B_),dim3(384),0,stream>>>(gi, whhf, bhhf, (const int*)d_in[4], flag, d_out);
}

// Round 3
// 307.464 us; speedup vs baseline: 1.7283x; 1.1445x over previous
//
#include <hip/hip_runtime.h>
#include <hip/hip_bf16.h>

#define B_ 32
#define T_ 256
#define D_ 64
#define H_ 128
#define G_ 384   // 3*H

typedef __hip_bfloat16 bf16;
typedef _Float16 half8 __attribute__((ext_vector_type(8)));
typedef float float4v __attribute__((ext_vector_type(4)));

__device__ __forceinline__ float ldsel(const void* p, int i, int bf) {
  if (bf) return __bfloat162float(((const bf16*)p)[i]);
  return ((const float*)p)[i];
}
__device__ __forceinline__ float fsigmoid(float x){ return 1.0f/(1.0f+__expf(-x)); }
__device__ __forceinline__ float ftanh_(float x){ return 1.0f - 2.0f/(1.0f+__expf(2.0f*x)); }

// flag=1 -> inputs are bf16; flag=0 -> f32 (missing_mask in f32 is exactly {0,1}).
__global__ void __launch_bounds__(256) detect_k(const unsigned* words, int n, int* flag){
  int bad = 0;
  for (int i = blockIdx.x*blockDim.x + threadIdx.x; i < n; i += gridDim.x*blockDim.x){
    float f = __uint_as_float(words[i]);
    bad |= !(f == 0.0f || f == 1.0f);
  }
  if (bad) atomicOr(flag, 1);
}

__global__ void __launch_bounds__(256) convert_k(
    const void* x, const void* mm, const void* vt,
    const void* E, const void* wih, const void* whh,
    const void* bih, const void* bhh, const int* flag,
    float* xo, float* vtf, float* Ef, float* wihf, float* whhf,
    float* bihf, float* bhhf){
  int bf = *flag;
  int stride = gridDim.x*blockDim.x;
  int t0 = blockIdx.x*blockDim.x + threadIdx.x;
  for (int i = t0; i < B_*T_*D_; i += stride)
    xo[i] = ldsel(x,i,bf) * (1.0f - ldsel(mm,i,bf));   // x * observed
  for (int i = t0; i < B_*T_; i += stride) vtf[i] = ldsel(vt,i,bf);
  for (int i = t0; i < D_*H_; i += stride) Ef[i]  = ldsel(E,i,bf);
  for (int i = t0; i < G_*H_; i += stride) wihf[i] = ldsel(wih,i,bf);
  for (int i = t0; i < G_*H_; i += stride) whhf[i] = ldsel(whh,i,bf);
  for (int i = t0; i < G_;    i += stride) bihf[i] = ldsel(bih,i,bf);
  for (int i = t0; i < G_;    i += stride) bhhf[i] = ldsel(bhh,i,bf);
}

// wcol[b,j] = column sums of the row-normalized adjacency (see R1 derivation).
__global__ void __launch_bounds__(256) adj_k(const void* mm, const int* flag,
                                             const float* Ef, float* wcol){
  int b = blockIdx.x;
  int tid = threadIdx.x;
  int d = tid & 63, q = tid >> 6;
  int bf = *flag;
  __shared__ float spp[4][64];
  __shared__ float sp[64];
  __shared__ float sE[64*129];
  __shared__ float ssim[64*65];
  __shared__ float srs[64];
  float p = 0.0f;
  if (bf){
    const bf16* m = (const bf16*)mm;
    for (int t = q*64; t < q*64+64; t++) p += 1.0f - __bfloat162float(m[(b*T_ + t)*D_ + d]);
  } else {
    const float* m = (const float*)mm;
    for (int t = q*64; t < q*64+64; t++) p += 1.0f - m[(b*T_ + t)*D_ + d];
  }
  spp[q][d] = p;
  for (int i = tid; i < D_*H_; i += 256){ int r = i >> 7, c = i & 127; sE[r*129+c] = Ef[i]; }
  __syncthreads();
  if (tid < 64) sp[tid] = (spp[0][tid]+spp[1][tid]+spp[2][tid]+spp[3][tid]) * (1.0f/T_);
  __syncthreads();
  float rowE[128];
  #pragma unroll
  for (int k = 0; k < 128; k++) rowE[k] = sE[d*129+k];
  for (int i = q*16; i < q*16+16; i++){
    float s = 0.0f;
    #pragma unroll
    for (int k = 0; k < 128; k++) s += rowE[k]*sE[i*129+k];
    ssim[d*65+i] = fmaxf(s, 0.0f);
  }
  __syncthreads();
  if (tid < 64){
    float rs = 0.0f;
    for (int j = 0; j < 64; j++) rs += sp[j]*ssim[tid*65+j];
    srs[tid] = fmaxf(sp[tid]*rs + 1.0f, 1e-6f);
  }
  __syncthreads();
  if (tid < 64){
    float s = 0.0f;
    for (int i = 0; i < 64; i++) s += sp[i]*ssim[tid*65+i]/srs[i];
    wcol[b*64 + tid] = sp[tid]*s + 1.0f/srs[tid];
  }
}

// visit_repr + time encoding + input-side GRU GEMM, fused.
// Writes gi TRANSPOSED: gi3[b][g][t] so gru_k can chunk-prefetch t-contiguous.
__global__ void __launch_bounds__(384,1) gi_k(const float* xo, const float* vtf,
                                              const float* Ef, const float* wihf,
                                              const float* bihf, const float* wcol,
                                              float* gi3){
  int bid = blockIdx.x;
  int b = bid >> 3, t0 = (bid & 7)*32;
  int tid = threadIdx.x;
  __shared__ float sE[D_*H_];
  __shared__ float sv[32*D_];
  __shared__ float svr[32*H_];
  __shared__ float sw[D_];
  for (int i = tid; i < D_*H_; i += 384) sE[i] = Ef[i];
  if (tid < D_) sw[tid] = wcol[b*D_ + tid];
  __syncthreads();
  for (int i = tid; i < 32*D_; i += 384){
    int r = i >> 6, j = i & 63;
    sv[i] = xo[(b*T_ + t0 + r)*D_ + j] * sw[j];
  }
  __syncthreads();
  int h = tid & 127, rg = tid >> 7;
  float fr = __expf(-(float)(h & 63) * 0.14391157f);   // ln(1e4)/64
  for (int r = rg; r < 32; r += 3){
    float acc = 0.0f;
    #pragma unroll
    for (int j = 0; j < D_; j++) acc += sv[r*D_+j] * sE[j*H_+h];
    float ang = vtf[b*T_ + t0 + r] * fr;
    float e = (h < 64) ? __sinf(ang) : __cosf(ang);
    svr[r*H_+h] = acc * (1.0f/D_) + e;
  }
  __syncthreads();
  float wr[H_];
  #pragma unroll
  for (int k = 0; k < H_; k += 4){
    float4 v = *(const float4*)&wihf[tid*H_ + k];
    wr[k]=v.x; wr[k+1]=v.y; wr[k+2]=v.z; wr[k+3]=v.w;
  }
  float bi = bihf[tid];
  float acc[32];
  #pragma unroll
  for (int r = 0; r < 32; r++) acc[r] = 0.0f;
  #pragma unroll
  for (int k4 = 0; k4 < 32; k4++){
    float w0 = wr[k4*4], w1 = wr[k4*4+1], w2 = wr[k4*4+2], w3 = wr[k4*4+3];
    #pragma unroll
    for (int r = 0; r < 32; r++){
      float4 hv = *(const float4*)&svr[r*H_ + k4*4];   // broadcast
      acc[r] += w0*hv.x + w1*hv.y + w2*hv.z + w3*hv.w;
    }
  }
  long gb = ((long)b*G_ + tid)*T_ + t0;
  #pragma unroll
  for (int q = 0; q < 8; q++){
    float4 v;
    v.x = acc[q*4]   + bi; v.y = acc[q*4+1] + bi;
    v.z = acc[q*4+2] + bi; v.w = acc[q*4+3] + bi;
    *(float4*)&gi3[gb + q*4] = v;
  }
}

// Sequential GRU v3: per-batch block, 4 waves (1/SIMD), ONE barrier/step.
// Wave w owns six 16-wide N-tiles: {32w,32w+16} of each gate part (r/z/n),
// so lane l<32 extracts its own gate triple from the accumulators via a
// (l&16) select -- gh never touches LDS. h ping-pongs between two f16 LDS
// buffers (read hb[t&1], write hb[t&1^1]); h carried in f32 regs.
// gi prefetched 8 steps/chunk from transposed gi3[b][g][t], double-buffered;
// out buffered 8 steps in regs and flushed per chunk (amortized vmcnt drain).
__global__ void __launch_bounds__(256,1) gru_k(const float* gi3, const float* whhf,
                                               const float* bhhf, const int* lengths,
                                               const int* flag, void* out){
  int b = blockIdx.x;
  int tid = threadIdx.x;
  int w = tid >> 6, l = tid & 63;
  int lq = l >> 4, lm = l & 15;
  int bf = *flag;
  int len = lengths[b];
  bool gate = (l < 32);
  int j = 32*w + l;              // gate index when gate==true

  __shared__ __align__(16) _Float16 hb[2][H_];

  // B-frags: tile i base Nb[i]; B[k][n] = W_hh[Nb[i]+n][k]
  const int Nb0 = 32*w;
  half8 bfrag[6][4];
  #pragma unroll
  for (int i = 0; i < 6; i++){
    int nb = Nb0 + (i>>1)*H_ + (i&1)*16;     // {32w,32w+16, +128, +144, +256, +272}
    int row = nb + lm;
    #pragma unroll
    for (int kc = 0; kc < 4; kc++){
      const float* src = &whhf[row*H_ + kc*32 + lq*8];
      float4 x0 = *(const float4*)src;
      float4 x1 = *(const float4*)(src+4);
      half8 f;
      f[0]=(_Float16)x0.x; f[1]=(_Float16)x0.y; f[2]=(_Float16)x0.z; f[3]=(_Float16)x0.w;
      f[4]=(_Float16)x1.x; f[5]=(_Float16)x1.y; f[6]=(_Float16)x1.z; f[7]=(_Float16)x1.w;
      bfrag[i][kc] = f;
    }
  }
  float br=0, bz=0, bn=0;
  const float* pr = nullptr; const float* pz; const float* pn;
  if (gate){
    br = bhhf[j]; bz = bhhf[H_ + j]; bn = bhhf[2*H_ + j];
    pr = gi3 + ((long)b*G_ + j)*T_;
    pz = pr + (long)H_*T_;
    pn = pr + (long)2*H_*T_;
  }

  if (tid < H_) hb[0][tid] = (_Float16)0.0f;

  float gr[2][8], gz[2][8], gn[2][8];
  if (gate){
    float4 a0 = *(const float4*)(pr);  float4 a1 = *(const float4*)(pr+4);
    float4 b0 = *(const float4*)(pz);  float4 b1 = *(const float4*)(pz+4);
    float4 c0 = *(const float4*)(pn);  float4 c1 = *(const float4*)(pn+4);
    gr[0][0]=a0.x; gr[0][1]=a0.y; gr[0][2]=a0.z; gr[0][3]=a0.w;
    gr[0][4]=a1.x; gr[0][5]=a1.y; gr[0][6]=a1.z; gr[0][7]=a1.w;
    gz[0][0]=b0.x; gz[0][1]=b0.y; gz[0][2]=b0.z; gz[0][3]=b0.w;
    gz[0][4]=b1.x; gz[0][5]=b1.y; gz[0][6]=b1.z; gz[0][7]=b1.w;
    gn[0][0]=c0.x; gn[0][1]=c0.y; gn[0][2]=c0.z; gn[0][3]=c0.w;
    gn[0][4]=c1.x; gn[0][5]=c1.y; gn[0][6]=c1.z; gn[0][7]=c1.w;
  }
  __syncthreads();

  float hval = 0.0f;
  float ho[8];
  int cb = 0;
  for (int c = 0; c < 32; c++){
    if (gate && c+1 < 32){
      int nb2 = (c+1)*8;
      float4 a0 = *(const float4*)(pr+nb2);  float4 a1 = *(const float4*)(pr+nb2+4);
      float4 b0 = *(const float4*)(pz+nb2);  float4 b1 = *(const float4*)(pz+nb2+4);
      float4 c0 = *(const float4*)(pn+nb2);  float4 c1 = *(const float4*)(pn+nb2+4);
      int nc = cb^1;
      gr[nc][0]=a0.x; gr[nc][1]=a0.y; gr[nc][2]=a0.z; gr[nc][3]=a0.w;
      gr[nc][4]=a1.x; gr[nc][5]=a1.y; gr[nc][6]=a1.z; gr[nc][7]=a1.w;
      gz[nc][0]=b0.x; gz[nc][1]=b0.y; gz[nc][2]=b0.z; gz[nc][3]=b0.w;
      gz[nc][4]=b1.x; gz[nc][5]=b1.y; gz[nc][6]=b1.z; gz[nc][7]=b1.w;
      gn[nc][0]=c0.x; gn[nc][1]=c0.y; gn[nc][2]=c0.z; gn[nc][3]=c0.w;
      gn[nc][4]=c1.x; gn[nc][5]=c1.y; gn[nc][6]=c1.z; gn[nc][7]=c1.w;
    }
    #pragma unroll
    for (int i = 0; i < 8; i++){
      int t = c*8 + i;
      int rp = i & 1;            // read hb[rp], write hb[rp^1]
      half8 a0v = *(const half8*)&hb[rp][0*32 + lq*8];
      half8 a1v = *(const half8*)&hb[rp][1*32 + lq*8];
      half8 a2v = *(const half8*)&hb[rp][2*32 + lq*8];
      half8 a3v = *(const half8*)&hb[rp][3*32 + lq*8];
      float4v cc[6];
      #pragma unroll
      for (int q = 0; q < 6; q++) cc[q] = (float4v){0,0,0,0};
      #pragma unroll
      for (int q = 0; q < 6; q++) cc[q] = __builtin_amdgcn_mfma_f32_16x16x32_f16(a0v, bfrag[q][0], cc[q], 0,0,0);
      #pragma unroll
      for (int q = 0; q < 6; q++) cc[q] = __builtin_amdgcn_mfma_f32_16x16x32_f16(a1v, bfrag[q][1], cc[q], 0,0,0);
      #pragma unroll
      for (int q = 0; q < 6; q++) cc[q] = __builtin_amdgcn_mfma_f32_16x16x32_f16(a2v, bfrag[q][2], cc[q], 0,0,0);
      #pragma unroll
      for (int q = 0; q < 6; q++) cc[q] = __builtin_amdgcn_mfma_f32_16x16x32_f16(a3v, bfrag[q][3], cc[q], 0,0,0);
      float ghr = (l & 16) ? cc[1][0] : cc[0][0];
      float ghz = (l & 16) ? cc[3][0] : cc[2][0];
      float ghn = (l & 16) ? cc[5][0] : cc[4][0];
      if (gate){
        float r = fsigmoid(gr[cb][i] + ghr + br);
        float z = fsigmoid(gz[cb][i] + ghz + bz);
        float n = ftanh_(gn[cb][i] + r*(ghn + bn));
        hval = (1.0f - z)*n + z*hval;
        hb[rp^1][j] = (_Float16)hval;
        ho[i] = (t < len) ? hval : 0.0f;
      }
      __syncthreads();
    }
    if (gate){
      long ob = ((long)b*T_ + c*8)*H_ + j;
      if (bf){
        #pragma unroll
        for (int i = 0; i < 8; i++) ((bf16*)out)[ob + (long)i*H_] = __float2bfloat16(ho[i]);
      } else {
        #pragma unroll
        for (int i = 0; i < 8; i++) ((float*)out)[ob + (long)i*H_] = ho[i];
      }
    }
    cb ^= 1;
  }
}

extern "C" void kernel_launch(void* const* d_in, const int* in_sizes, int n_in,
                              void* d_out, int out_size, void* d_ws, size_t ws_size,
                              hipStream_t stream) {
  char* base = (char*)d_ws;
  size_t off = 0;
  auto alloc = [&](size_t bytes)->void*{
    void* p = base + off; off = (off + bytes + 255) & ~(size_t)255; return p;
  };
  int*   flag = (int*)  alloc(4);
  float* xo   = (float*)alloc((size_t)B_*T_*D_*4);
  float* vtf  = (float*)alloc((size_t)B_*T_*4);
  float* Ef   = (float*)alloc((size_t)D_*H_*4);
  float* wihf = (float*)alloc((size_t)G_*H_*4);
  float* whhf = (float*)alloc((size_t)G_*H_*4);
  float* bihf = (float*)alloc((size_t)G_*4);
  float* bhhf = (float*)alloc((size_t)G_*4);
  float* wcol = (float*)alloc((size_t)B_*D_*4);
  float* gi3  = (float*)alloc((size_t)B_*G_*T_*4);
  if (off > ws_size) return;

  hipMemsetAsync(flag, 0, 4, stream);
  detect_k<<<dim3(256),dim3(256),0,stream>>>((const unsigned*)d_in[1], (B_*T_*D_)/2, flag);
  convert_k<<<dim3(256),dim3(256),0,stream>>>(d_in[0], d_in[1], d_in[2], d_in[5],
                                              d_in[6], d_in[7], d_in[8], d_in[9],
                                              flag, xo, vtf, Ef, wihf, whhf, bihf, bhhf);
  adj_k<<<dim3(B_),dim3(256),0,stream>>>(d_in[1], flag, Ef, wcol);
  gi_k<<<dim3(256),dim3(384),0,stream>>>(xo, vtf, Ef, wihf, bihf, wcol, gi3);
  gru_k<<<dim3(B_),dim3(256),0,stream>>>(gi3, whhf, bhhf, (const int*)d_in[4], flag, d_out);
}

// Round 4
// 281.561 us; speedup vs baseline: 1.8873x; 1.0920x over previous
//
#include <hip/hip_runtime.h>
#include <hip/hip_bf16.h>

#define B_ 32
#define T_ 256
#define D_ 64
#define H_ 128
#define G_ 384   // 3*H

typedef __hip_bfloat16 bf16;
typedef _Float16 half8 __attribute__((ext_vector_type(8)));
typedef _Float16 half4v __attribute__((ext_vector_type(4)));
typedef float float4v __attribute__((ext_vector_type(4)));

__device__ __forceinline__ float ldsel(const void* p, int i, int bf) {
  if (bf) return __bfloat162float(((const bf16*)p)[i]);
  return ((const float*)p)[i];
}
__device__ __forceinline__ float fsigmoid(float x){ return 1.0f/(1.0f+__expf(-x)); }
__device__ __forceinline__ float ftanh_(float x){ return 1.0f - 2.0f/(1.0f+__expf(2.0f*x)); }

// flag=1 -> inputs are bf16; flag=0 -> f32 (missing_mask in f32 is exactly {0,1}).
__global__ void __launch_bounds__(256) detect_k(const unsigned* words, int n, int* flag){
  int bad = 0;
  for (int i = blockIdx.x*blockDim.x + threadIdx.x; i < n; i += gridDim.x*blockDim.x){
    float f = __uint_as_float(words[i]);
    bad |= !(f == 0.0f || f == 1.0f);
  }
  if (bad) atomicOr(flag, 1);
}

__global__ void __launch_bounds__(256) convert_k(
    const void* x, const void* mm, const void* vt,
    const void* E, const void* wih, const void* whh,
    const void* bih, const void* bhh, const int* flag,
    float* xo, float* vtf, float* Ef, float* wihf, float* whhf,
    float* bihf, float* bhhf){
  int bf = *flag;
  int stride = gridDim.x*blockDim.x;
  int t0 = blockIdx.x*blockDim.x + threadIdx.x;
  for (int i = t0; i < B_*T_*D_; i += stride)
    xo[i] = ldsel(x,i,bf) * (1.0f - ldsel(mm,i,bf));   // x * observed
  for (int i = t0; i < B_*T_; i += stride) vtf[i] = ldsel(vt,i,bf);
  for (int i = t0; i < D_*H_; i += stride) Ef[i]  = ldsel(E,i,bf);
  for (int i = t0; i < G_*H_; i += stride) wihf[i] = ldsel(wih,i,bf);
  for (int i = t0; i < G_*H_; i += stride) whhf[i] = ldsel(whh,i,bf);
  for (int i = t0; i < G_;    i += stride) bihf[i] = ldsel(bih,i,bf);
  for (int i = t0; i < G_;    i += stride) bhhf[i] = ldsel(bhh,i,bf);
}

// wcol[b,j] = column sums of the row-normalized adjacency, * (1/D) folded later.
__global__ void __launch_bounds__(256) adj_k(const void* mm, const int* flag,
                                             const float* Ef, float* wcol){
  int b = blockIdx.x;
  int tid = threadIdx.x;
  int d = tid & 63, q = tid >> 6;
  int bf = *flag;
  __shared__ float spp[4][64];
  __shared__ float sp[64];
  __shared__ float sE[64*129];
  __shared__ float ssim[64*65];
  __shared__ float srs[64];
  float p = 0.0f;
  if (bf){
    const bf16* m = (const bf16*)mm;
    for (int t = q*64; t < q*64+64; t++) p += 1.0f - __bfloat162float(m[(b*T_ + t)*D_ + d]);
  } else {
    const float* m = (const float*)mm;
    for (int t = q*64; t < q*64+64; t++) p += 1.0f - m[(b*T_ + t)*D_ + d];
  }
  spp[q][d] = p;
  for (int i = tid; i < D_*H_; i += 256){ int r = i >> 7, c = i & 127; sE[r*129+c] = Ef[i]; }
  __syncthreads();
  if (tid < 64) sp[tid] = (spp[0][tid]+spp[1][tid]+spp[2][tid]+spp[3][tid]) * (1.0f/T_);
  __syncthreads();
  float rowE[128];
  #pragma unroll
  for (int k = 0; k < 128; k++) rowE[k] = sE[d*129+k];
  for (int i = q*16; i < q*16+16; i++){
    float s = 0.0f;
    #pragma unroll
    for (int k = 0; k < 128; k++) s += rowE[k]*sE[i*129+k];
    ssim[d*65+i] = fmaxf(s, 0.0f);
  }
  __syncthreads();
  if (tid < 64){
    float rs = 0.0f;
    for (int j = 0; j < 64; j++) rs += sp[j]*ssim[tid*65+j];
    srs[tid] = fmaxf(sp[tid]*rs + 1.0f, 1e-6f);
  }
  __syncthreads();
  if (tid < 64){
    float s = 0.0f;
    for (int i = 0; i < 64; i++) s += sp[i]*ssim[tid*65+i]/srs[i];
    wcol[b*64 + tid] = sp[tid]*s + 1.0f/srs[tid];
  }
}

// gi_k v2: both phases as MFMA GEMMs. 256 blocks (b x 8 t-chunks of 32), 512 thr.
// Phase A: vr[32t][128h] = (xo*w/64)[32t][64d] x E[64d][128h] + time-enc -> f16 LDS.
// Phase B: gi[32t][384g] = vr[32t][128k] x W_ih[384g][128k]^T + (bih + bhh[r,z]).
// gi3 written transposed [b][g][t] (dwordx4 of 4 consecutive t per lane).
#define AVP 72    // av pitch (f16): 144B = 9*16 -> aligned b128, 2-way banks (free)
#define VRP 136   // vrA pitch (f16): 272B = 17*16 -> aligned b128, 2-way banks
__global__ void __launch_bounds__(512,1) gi_k(const float* xo, const float* vtf,
                                              const float* Ef, const float* wihf,
                                              const float* bihf, const float* bhhf,
                                              const float* wcol, float* gi3){
  int bid = blockIdx.x;
  int b = bid >> 3, t0 = (bid & 7)*32;
  int tid = threadIdx.x;
  int w = tid >> 6, l = tid & 63;
  int lq = l >> 4, lm = l & 15;

  __shared__ __align__(16) _Float16 av[32*AVP];
  __shared__ __align__(16) _Float16 vrA[32*VRP];
  __shared__ float sVt[32];

  // stage av[t][d] = xo[b][t0+t][d] * wcol[b][d] / 64   (f16)
  {
    int t = tid >> 4, d4 = (tid & 15)*4;
    float4 xv = *(const float4*)&xo[((long)(b*T_ + t0 + t))*D_ + d4];
    float4 wv = *(const float4*)&wcol[b*D_ + d4];
    half4v h;
    h[0]=(_Float16)(xv.x*wv.x*(1.0f/64)); h[1]=(_Float16)(xv.y*wv.y*(1.0f/64));
    h[2]=(_Float16)(xv.z*wv.z*(1.0f/64)); h[3]=(_Float16)(xv.w*wv.w*(1.0f/64));
    *(half4v*)&av[t*AVP + d4] = h;
  }
  if (tid < 32) sVt[tid] = vtf[b*T_ + t0 + tid];
  // Phase A B-frags: B[k=d][n] = E[d][16w+n]  (gathers, one-time)
  half8 bE[2];
  #pragma unroll
  for (int kc = 0; kc < 2; kc++){
    half8 f;
    #pragma unroll
    for (int jj = 0; jj < 8; jj++)
      f[jj] = (_Float16)Ef[(kc*32 + lq*8 + jj)*H_ + 16*w + lm];
    bE[kc] = f;
  }
  __syncthreads();

  // Phase A MFMAs: M=32 (2 tiles), N=16 (this wave's h-chunk), K=64
  float4v accA[2] = {{0,0,0,0},{0,0,0,0}};
  #pragma unroll
  for (int kc = 0; kc < 2; kc++){
    #pragma unroll
    for (int mt = 0; mt < 2; mt++){
      half8 a = *(const half8*)&av[(mt*16+lm)*AVP + kc*32 + lq*8];
      accA[mt] = __builtin_amdgcn_mfma_f32_16x16x32_f16(a, bE[kc], accA[mt], 0,0,0);
    }
  }
  // epilogue: + time encoding, write vrA f16
  {
    int h = 16*w + lm;
    float fr = __expf(-(float)(h & 63) * 0.14391157f);   // ln(1e4)/64
    #pragma unroll
    for (int mt = 0; mt < 2; mt++){
      #pragma unroll
      for (int r = 0; r < 4; r++){
        int tl = mt*16 + lq*4 + r;
        float ang = sVt[tl] * fr;
        float e = (h < 64) ? __sinf(ang) : __cosf(ang);
        vrA[tl*VRP + h] = (_Float16)(accA[mt][r] + e);
      }
    }
  }
  __syncthreads();

  // Phase B: wave owns N-tiles 3w..3w+2 (g-chunks of 16)
  half8 bW[3][4]; float biW[3];
  #pragma unroll
  for (int q = 0; q < 3; q++){
    int g = 16*(3*w + q) + lm;
    biW[q] = bihf[g] + (g < 2*H_ ? bhhf[g] : 0.0f);   // fold b_hh for r,z
    #pragma unroll
    for (int kc = 0; kc < 4; kc++){
      const float* src = &wihf[(long)g*H_ + kc*32 + lq*8];
      float4 x0 = *(const float4*)src;
      float4 x1 = *(const float4*)(src+4);
      half8 f;
      f[0]=(_Float16)x0.x; f[1]=(_Float16)x0.y; f[2]=(_Float16)x0.z; f[3]=(_Float16)x0.w;
      f[4]=(_Float16)x1.x; f[5]=(_Float16)x1.y; f[6]=(_Float16)x1.z; f[7]=(_Float16)x1.w;
      bW[q][kc] = f;
    }
  }
  float4v cB[2][3];
  #pragma unroll
  for (int mt = 0; mt < 2; mt++)
    #pragma unroll
    for (int q = 0; q < 3; q++) cB[mt][q] = (float4v){0,0,0,0};
  #pragma unroll
  for (int kc = 0; kc < 4; kc++){
    #pragma unroll
    for (int mt = 0; mt < 2; mt++){
      half8 a = *(const half8*)&vrA[(mt*16+lm)*VRP + kc*32 + lq*8];
      #pragma unroll
      for (int q = 0; q < 3; q++)
        cB[mt][q] = __builtin_amdgcn_mfma_f32_16x16x32_f16(a, bW[q][kc], cB[mt][q], 0,0,0);
    }
  }
  #pragma unroll
  for (int mt = 0; mt < 2; mt++){
    #pragma unroll
    for (int q = 0; q < 3; q++){
      int g = 16*(3*w + q) + lm;
      int tb = t0 + mt*16 + lq*4;
      float4 v;
      v.x = cB[mt][q][0] + biW[q]; v.y = cB[mt][q][1] + biW[q];
      v.z = cB[mt][q][2] + biW[q]; v.w = cB[mt][q][3] + biW[q];
      *(float4*)&gi3[((long)(b*G_ + g))*T_ + tb] = v;
    }
  }
}

// Sequential GRU v4: per-batch block, 512 thr = 8 waves = 2 waves/SIMD (TLP
// hides the per-step serial stalls behind the other wave's MFMA issue).
// Wave w owns one 16-wide N-tile per gate part: j in [16w,16w+16), 12 MFMAs.
// Gate lanes l<16 extract their triple from accumulators (no LDS for gh).
// h ping-pongs between two f16 LDS buffers; one barrier per step.
// b_hh for r,z pre-folded into gi3 by gi_k; bn added to ghn here.
__global__ void __launch_bounds__(512,2) gru_k(const float* gi3, const float* whhf,
                                               const float* bhhf, const int* lengths,
                                               const int* flag, void* out){
  int b = blockIdx.x;
  int tid = threadIdx.x;
  int w = tid >> 6, l = tid & 63;
  int lq = l >> 4, lm = l & 15;
  int bf = *flag;
  int len = lengths[b];
  bool gate = (l < 16);
  int j = 16*w + l;              // gate index when gate==true (bijective over 0..127)

  __shared__ __align__(16) _Float16 hb[2][H_];

  // B-frags: part p (r/z/n) tile base nb = p*128 + 16w; B[k][n] = W_hh[nb+n][k]
  half8 bfrag[3][4];
  #pragma unroll
  for (int p = 0; p < 3; p++){
    int row = p*H_ + 16*w + lm;
    #pragma unroll
    for (int kc = 0; kc < 4; kc++){
      const float* src = &whhf[(long)row*H_ + kc*32 + lq*8];
      float4 x0 = *(const float4*)src;
      float4 x1 = *(const float4*)(src+4);
      half8 f;
      f[0]=(_Float16)x0.x; f[1]=(_Float16)x0.y; f[2]=(_Float16)x0.z; f[3]=(_Float16)x0.w;
      f[4]=(_Float16)x1.x; f[5]=(_Float16)x1.y; f[6]=(_Float16)x1.z; f[7]=(_Float16)x1.w;
      bfrag[p][kc] = f;
    }
  }
  float bn_ = 0.0f;
  const float* pr = nullptr; const float* pz; const float* pn;
  if (gate){
    bn_ = bhhf[2*H_ + j];
    pr = gi3 + ((long)b*G_ + j)*T_;
    pz = pr + (long)H_*T_;
    pn = pr + (long)2*H_*T_;
  }
  if (tid < H_) hb[0][tid] = (_Float16)0.0f;

  float gr[2][8], gz[2][8], gn[2][8];
  if (gate){
    float4 a0 = *(const float4*)(pr);  float4 a1 = *(const float4*)(pr+4);
    float4 b0 = *(const float4*)(pz);  float4 b1 = *(const float4*)(pz+4);
    float4 c0 = *(const float4*)(pn);  float4 c1 = *(const float4*)(pn+4);
    gr[0][0]=a0.x; gr[0][1]=a0.y; gr[0][2]=a0.z; gr[0][3]=a0.w;
    gr[0][4]=a1.x; gr[0][5]=a1.y; gr[0][6]=a1.z; gr[0][7]=a1.w;
    gz[0][0]=b0.x; gz[0][1]=b0.y; gz[0][2]=b0.z; gz[0][3]=b0.w;
    gz[0][4]=b1.x; gz[0][5]=b1.y; gz[0][6]=b1.z; gz[0][7]=b1.w;
    gn[0][0]=c0.x; gn[0][1]=c0.y; gn[0][2]=c0.z; gn[0][3]=c0.w;
    gn[0][4]=c1.x; gn[0][5]=c1.y; gn[0][6]=c1.z; gn[0][7]=c1.w;
  }
  __syncthreads();

  float hval = 0.0f;
  float ho[8];
  int cb = 0;
  for (int c = 0; c < 32; c++){
    if (gate && c+1 < 32){
      int nb2 = (c+1)*8;
      float4 a0 = *(const float4*)(pr+nb2);  float4 a1 = *(const float4*)(pr+nb2+4);
      float4 b0 = *(const float4*)(pz+nb2);  float4 b1 = *(const float4*)(pz+nb2+4);
      float4 c0 = *(const float4*)(pn+nb2);  float4 c1 = *(const float4*)(pn+nb2+4);
      int nc = cb^1;
      gr[nc][0]=a0.x; gr[nc][1]=a0.y; gr[nc][2]=a0.z; gr[nc][3]=a0.w;
      gr[nc][4]=a1.x; gr[nc][5]=a1.y; gr[nc][6]=a1.z; gr[nc][7]=a1.w;
      gz[nc][0]=b0.x; gz[nc][1]=b0.y; gz[nc][2]=b0.z; gz[nc][3]=b0.w;
      gz[nc][4]=b1.x; gz[nc][5]=b1.y; gz[nc][6]=b1.z; gz[nc][7]=b1.w;
      gn[nc][0]=c0.x; gn[nc][1]=c0.y; gn[nc][2]=c0.z; gn[nc][3]=c0.w;
      gn[nc][4]=c1.x; gn[nc][5]=c1.y; gn[nc][6]=c1.z; gn[nc][7]=c1.w;
    }
    #pragma unroll
    for (int i = 0; i < 8; i++){
      int rp = i & 1;            // read hb[rp], write hb[rp^1]
      half8 a0v = *(const half8*)&hb[rp][0*32 + lq*8];
      half8 a1v = *(const half8*)&hb[rp][1*32 + lq*8];
      half8 a2v = *(const half8*)&hb[rp][2*32 + lq*8];
      half8 a3v = *(const half8*)&hb[rp][3*32 + lq*8];
      float4v cc[3];
      #pragma unroll
      for (int p = 0; p < 3; p++) cc[p] = (float4v){0,0,0,0};
      #pragma unroll
      for (int p = 0; p < 3; p++) cc[p] = __builtin_amdgcn_mfma_f32_16x16x32_f16(a0v, bfrag[p][0], cc[p], 0,0,0);
      #pragma unroll
      for (int p = 0; p < 3; p++) cc[p] = __builtin_amdgcn_mfma_f32_16x16x32_f16(a1v, bfrag[p][1], cc[p], 0,0,0);
      #pragma unroll
      for (int p = 0; p < 3; p++) cc[p] = __builtin_amdgcn_mfma_f32_16x16x32_f16(a2v, bfrag[p][2], cc[p], 0,0,0);
      #pragma unroll
      for (int p = 0; p < 3; p++) cc[p] = __builtin_amdgcn_mfma_f32_16x16x32_f16(a3v, bfrag[p][3], cc[p], 0,0,0);
      if (gate){
        float r = fsigmoid(gr[cb][i] + cc[0][0]);
        float z = fsigmoid(gz[cb][i] + cc[1][0]);
        float n = ftanh_(gn[cb][i] + r*(cc[2][0] + bn_));
        hval = (1.0f - z)*n + z*hval;
        hb[rp^1][j] = (_Float16)hval;
        ho[i] = (c*8 + i < len) ? hval : 0.0f;
      }
      __syncthreads();
    }
    if (gate){
      long ob = ((long)b*T_ + c*8)*H_ + j;
      if (bf){
        #pragma unroll
        for (int i = 0; i < 8; i++) ((bf16*)out)[ob + (long)i*H_] = __float2bfloat16(ho[i]);
      } else {
        #pragma unroll
        for (int i = 0; i < 8; i++) ((float*)out)[ob + (long)i*H_] = ho[i];
      }
    }
    cb ^= 1;
  }
}

extern "C" void kernel_launch(void* const* d_in, const int* in_sizes, int n_in,
                              void* d_out, int out_size, void* d_ws, size_t ws_size,
                              hipStream_t stream) {
  char* base = (char*)d_ws;
  size_t off = 0;
  auto alloc = [&](size_t bytes)->void*{
    void* p = base + off; off = (off + bytes + 255) & ~(size_t)255; return p;
  };
  int*   flag = (int*)  alloc(4);
  float* xo   = (float*)alloc((size_t)B_*T_*D_*4);
  float* vtf  = (float*)alloc((size_t)B_*T_*4);
  float* Ef   = (float*)alloc((size_t)D_*H_*4);
  float* wihf = (float*)alloc((size_t)G_*H_*4);
  float* whhf = (float*)alloc((size_t)G_*H_*4);
  float* bihf = (float*)alloc((size_t)G_*4);
  float* bhhf = (float*)alloc((size_t)G_*4);
  float* wcol = (float*)alloc((size_t)B_*D_*4);
  float* gi3  = (float*)alloc((size_t)B_*G_*T_*4);
  if (off > ws_size) return;

  hipMemsetAsync(flag, 0, 4, stream);
  detect_k<<<dim3(256),dim3(256),0,stream>>>((const unsigned*)d_in[1], (B_*T_*D_)/2, flag);
  convert_k<<<dim3(256),dim3(256),0,stream>>>(d_in[0], d_in[1], d_in[2], d_in[5],
                                              d_in[6], d_in[7], d_in[8], d_in[9],
                                              flag, xo, vtf, Ef, wihf, whhf, bihf, bhhf);
  adj_k<<<dim3(B_),dim3(256),0,stream>>>(d_in[1], flag, Ef, wcol);
  gi_k<<<dim3(256),dim3(512),0,stream>>>(xo, vtf, Ef, wihf, bihf, bhhf, wcol, gi3);
  gru_k<<<dim3(B_),dim3(512),0,stream>>>(gi3, whhf, bhhf, (const int*)d_in[4], flag, d_out);
}

// Round 8
// 277.960 us; speedup vs baseline: 1.9118x; 1.0130x over previous
//
#include <hip/hip_runtime.h>
#include <hip/hip_bf16.h>

#define B_ 32
#define T_ 256
#define D_ 64
#define H_ 128
#define G_ 384   // 3*H

typedef _Float16 half8 __attribute__((ext_vector_type(8)));
typedef _Float16 half4v __attribute__((ext_vector_type(4)));
typedef float float4v __attribute__((ext_vector_type(4)));

__device__ __forceinline__ float fsigmoid(float x){ return 1.0f/(1.0f+__expf(-x)); }
__device__ __forceinline__ float ftanh_(float x){ return 1.0f - 2.0f/(1.0f+__expf(2.0f*x)); }

// NOTE (R5-R7 post-mortem): inputs/outputs are f32 — reference setup_inputs is
// all jnp.float32 and R1-R4's on-device detect kernel confirmed {0,1} f32 mask
// words. Reading them as bf16 was the NaN source (f32 mantissa bytes decode to
// bf16 NaN at ~1/256 rate). Do NOT switch dtypes without on-device evidence.

// wcol[b,j] = column sums of the row-normalized adjacency (R1 derivation):
// adj_raw[i,j] = p_i p_j sim_ij + I; rs_i = 1 + p_i*sum_j p_j sim_ij;
// wcol_j = p_j * sum_i p_i sim_ij / rs_i + 1/rs_j  (sim symmetric).
__global__ void __launch_bounds__(256) adj_k(const float* mm, const float* E,
                                             float* wcol){
  int b = blockIdx.x;
  int tid = threadIdx.x;
  int d = tid & 63, q = tid >> 6;
  __shared__ float spp[4][64];
  __shared__ float sp[64];
  __shared__ float sE[64*129];
  __shared__ float ssim[64*65];
  __shared__ float srs[64];
  float p = 0.0f;
  for (int t = q*64; t < q*64+64; t++) p += 1.0f - mm[(b*T_ + t)*D_ + d];
  spp[q][d] = p;
  for (int i = tid; i < D_*H_; i += 256){ int r = i >> 7, c = i & 127; sE[r*129+c] = E[i]; }
  __syncthreads();
  if (tid < 64) sp[tid] = (spp[0][tid]+spp[1][tid]+spp[2][tid]+spp[3][tid]) * (1.0f/T_);
  __syncthreads();
  float rowE[128];
  #pragma unroll
  for (int k = 0; k < 128; k++) rowE[k] = sE[d*129+k];
  for (int i = q*16; i < q*16+16; i++){
    float s = 0.0f;
    #pragma unroll
    for (int k = 0; k < 128; k++) s += rowE[k]*sE[i*129+k];
    ssim[d*65+i] = fmaxf(s, 0.0f);
  }
  __syncthreads();
  if (tid < 64){
    float rs = 0.0f;
    for (int j = 0; j < 64; j++) rs += sp[j]*ssim[tid*65+j];
    srs[tid] = fmaxf(sp[tid]*rs + 1.0f, 1e-6f);
  }
  __syncthreads();
  if (tid < 64){
    float s = 0.0f;
    for (int i = 0; i < 64; i++) s += sp[i]*ssim[tid*65+i]/srs[i];
    wcol[b*64 + tid] = sp[tid]*s + 1.0f/srs[tid];
  }
}

// gi_k v4 (f32 I/O): both phases MFMA GEMMs, 256 blocks (b x 8 t-chunks) x 512 thr.
// Phase A: vr[32t][128h] = (x*(1-mm)*wcol/64)[32t][64d] x E[64d][128h] + time-enc
// Phase B: gi[32t][384g] = vr x W_ih^T + (bih + bhh[r,z]); gi3 transposed [b][g][t].
#define AVP 72
#define VRP 136
__global__ void __launch_bounds__(512,1) gi_k(const float* x, const float* mm,
                                              const float* vt, const float* E,
                                              const float* wih, const float* bih,
                                              const float* bhh, const float* wcol,
                                              float* gi3){
  int bid = blockIdx.x;
  int b = bid >> 3, t0 = (bid & 7)*32;
  int tid = threadIdx.x;
  int w = tid >> 6, l = tid & 63;
  int lq = l >> 4, lm = l & 15;

  __shared__ __align__(16) _Float16 av[32*AVP];
  __shared__ __align__(16) _Float16 vrA[32*VRP];
  __shared__ float sVt[32];

  // stage av[t][d] = x*(1-mm)*wcol/64  (f32 in, f16 out)
  {
    int i = tid*4, t = i >> 6, d4 = i & 63;
    long src = (long)(b*T_ + t0 + t)*D_ + d4;
    float4 xv = *(const float4*)&x[src];
    float4 mv = *(const float4*)&mm[src];
    float4 wv = *(const float4*)&wcol[b*D_ + d4];
    half4v h;
    h[0]=(_Float16)(xv.x*(1.0f-mv.x)*wv.x*(1.0f/64));
    h[1]=(_Float16)(xv.y*(1.0f-mv.y)*wv.y*(1.0f/64));
    h[2]=(_Float16)(xv.z*(1.0f-mv.z)*wv.z*(1.0f/64));
    h[3]=(_Float16)(xv.w*(1.0f-mv.w)*wv.w*(1.0f/64));
    *(half4v*)&av[t*AVP + d4] = h;
  }
  if (tid < 32) sVt[tid] = vt[b*T_ + t0 + tid];
  // Phase A B-frags: B[k=d][n] = E[d][16w+n]  (one-time gather)
  half8 bE[2];
  #pragma unroll
  for (int kc = 0; kc < 2; kc++){
    half8 f;
    #pragma unroll
    for (int jj = 0; jj < 8; jj++)
      f[jj] = (_Float16)E[(kc*32 + lq*8 + jj)*H_ + 16*w + lm];
    bE[kc] = f;
  }
  __syncthreads();

  float4v accA[2] = {{0,0,0,0},{0,0,0,0}};
  #pragma unroll
  for (int kc = 0; kc < 2; kc++){
    #pragma unroll
    for (int mt = 0; mt < 2; mt++){
      half8 a = *(const half8*)&av[(mt*16+lm)*AVP + kc*32 + lq*8];
      accA[mt] = __builtin_amdgcn_mfma_f32_16x16x32_f16(a, bE[kc], accA[mt], 0,0,0);
    }
  }
  {
    int h = 16*w + lm;
    float fr = __expf(-(float)(h & 63) * 0.14391157f);   // ln(1e4)/64
    #pragma unroll
    for (int mt = 0; mt < 2; mt++){
      #pragma unroll
      for (int r = 0; r < 4; r++){
        int tl = mt*16 + lq*4 + r;
        float ang = sVt[tl] * fr;
        float e = (h < 64) ? __sinf(ang) : __cosf(ang);
        vrA[tl*VRP + h] = (_Float16)(accA[mt][r] + e);
      }
    }
  }
  __syncthreads();

  // Phase B: wave owns N-tiles 3w..3w+2
  half8 bW[3][4]; float biW[3];
  #pragma unroll
  for (int q = 0; q < 3; q++){
    int g = 16*(3*w + q) + lm;
    biW[q] = bih[g] + (g < 2*H_ ? bhh[g] : 0.0f);  // fold b_hh for r,z
    #pragma unroll
    for (int kc = 0; kc < 4; kc++){
      const float* src = &wih[(long)g*H_ + kc*32 + lq*8];
      float4 x0 = *(const float4*)src;
      float4 x1 = *(const float4*)(src+4);
      half8 f;
      f[0]=(_Float16)x0.x; f[1]=(_Float16)x0.y; f[2]=(_Float16)x0.z; f[3]=(_Float16)x0.w;
      f[4]=(_Float16)x1.x; f[5]=(_Float16)x1.y; f[6]=(_Float16)x1.z; f[7]=(_Float16)x1.w;
      bW[q][kc] = f;
    }
  }
  float4v cB[2][3];
  #pragma unroll
  for (int mt = 0; mt < 2; mt++)
    #pragma unroll
    for (int q = 0; q < 3; q++) cB[mt][q] = (float4v){0,0,0,0};
  #pragma unroll
  for (int kc = 0; kc < 4; kc++){
    #pragma unroll
    for (int mt = 0; mt < 2; mt++){
      half8 a = *(const half8*)&vrA[(mt*16+lm)*VRP + kc*32 + lq*8];
      #pragma unroll
      for (int q = 0; q < 3; q++)
        cB[mt][q] = __builtin_amdgcn_mfma_f32_16x16x32_f16(a, bW[q][kc], cB[mt][q], 0,0,0);
    }
  }
  #pragma unroll
  for (int mt = 0; mt < 2; mt++){
    #pragma unroll
    for (int q = 0; q < 3; q++){
      int g = 16*(3*w + q) + lm;
      int tb = t0 + mt*16 + lq*4;
      float4 v;
      v.x = cB[mt][q][0] + biW[q]; v.y = cB[mt][q][1] + biW[q];
      v.z = cB[mt][q][2] + biW[q]; v.w = cB[mt][q][3] + biW[q];
      *(float4*)&gi3[((long)(b*G_ + g))*T_ + tb] = v;
    }
  }
}

// Sequential GRU v8 (f32 I/O): 4 waves, wave w owns 6 N-tiles (2 per gate
// part), gate lanes l<32 extract their triple via (l&16) select. h ping-pongs
// between two f16 LDS buffers; __syncthreads per step (safe barrier); MFMA
// accumulation split into two depth-2 chains. gi prefetched 8 steps/chunk
// from transposed gi3; output buffered 8 steps and flushed per chunk.
__global__ void __launch_bounds__(256,1) gru_k(const float* gi3, const float* whh,
                                               const float* bhh, const int* lengths,
                                               float* out){
  int b = blockIdx.x;
  int tid = threadIdx.x;
  int w = tid >> 6, l = tid & 63;
  int lq = l >> 4, lm = l & 15;
  int len = lengths[b];
  bool gate = (l < 32);
  int j = 32*w + l;              // gate index when gate==true

  __shared__ __align__(16) _Float16 hb[2][H_];

  // B-frags: tile i base {32w, 32w+16} + part*128 ; B[k][n] = W_hh[nb+n][k]
  half8 bfrag[6][4];
  #pragma unroll
  for (int i = 0; i < 6; i++){
    int row = 32*w + (i>>1)*H_ + (i&1)*16 + lm;
    #pragma unroll
    for (int kc = 0; kc < 4; kc++){
      const float* src = &whh[(long)row*H_ + kc*32 + lq*8];
      float4 x0 = *(const float4*)src;
      float4 x1 = *(const float4*)(src+4);
      half8 f;
      f[0]=(_Float16)x0.x; f[1]=(_Float16)x0.y; f[2]=(_Float16)x0.z; f[3]=(_Float16)x0.w;
      f[4]=(_Float16)x1.x; f[5]=(_Float16)x1.y; f[6]=(_Float16)x1.z; f[7]=(_Float16)x1.w;
      bfrag[i][kc] = f;
    }
  }
  float bn_ = 0.0f;
  const float* pr = nullptr; const float* pz; const float* pn;
  if (gate){
    bn_ = bhh[2*H_ + j];
    pr = gi3 + ((long)b*G_ + j)*T_;
    pz = pr + (long)H_*T_;
    pn = pr + (long)2*H_*T_;
  }
  if (tid < H_){ hb[0][tid] = (_Float16)0.0f; hb[1][tid] = (_Float16)0.0f; }

  float gr[2][8], gz[2][8], gn[2][8];
  if (gate){
    float4 a0 = *(const float4*)(pr);  float4 a1 = *(const float4*)(pr+4);
    float4 b0 = *(const float4*)(pz);  float4 b1 = *(const float4*)(pz+4);
    float4 c0 = *(const float4*)(pn);  float4 c1 = *(const float4*)(pn+4);
    gr[0][0]=a0.x; gr[0][1]=a0.y; gr[0][2]=a0.z; gr[0][3]=a0.w;
    gr[0][4]=a1.x; gr[0][5]=a1.y; gr[0][6]=a1.z; gr[0][7]=a1.w;
    gz[0][0]=b0.x; gz[0][1]=b0.y; gz[0][2]=b0.z; gz[0][3]=b0.w;
    gz[0][4]=b1.x; gz[0][5]=b1.y; gz[0][6]=b1.z; gz[0][7]=b1.w;
    gn[0][0]=c0.x; gn[0][1]=c0.y; gn[0][2]=c0.z; gn[0][3]=c0.w;
    gn[0][4]=c1.x; gn[0][5]=c1.y; gn[0][6]=c1.z; gn[0][7]=c1.w;
  }
  __syncthreads();

  float hval = 0.0f;
  float ho[8];
  int cb = 0;
  for (int c = 0; c < 32; c++){
    if (gate && c+1 < 32){
      int nb2 = (c+1)*8;
      float4 a0 = *(const float4*)(pr+nb2);  float4 a1 = *(const float4*)(pr+nb2+4);
      float4 b0 = *(const float4*)(pz+nb2);  float4 b1 = *(const float4*)(pz+nb2+4);
      float4 c0 = *(const float4*)(pn+nb2);  float4 c1 = *(const float4*)(pn+nb2+4);
      int nc = cb^1;
      gr[nc][0]=a0.x; gr[nc][1]=a0.y; gr[nc][2]=a0.z; gr[nc][3]=a0.w;
      gr[nc][4]=a1.x; gr[nc][5]=a1.y; gr[nc][6]=a1.z; gr[nc][7]=a1.w;
      gz[nc][0]=b0.x; gz[nc][1]=b0.y; gz[nc][2]=b0.z; gz[nc][3]=b0.w;
      gz[nc][4]=b1.x; gz[nc][5]=b1.y; gz[nc][6]=b1.z; gz[nc][7]=b1.w;
      gn[nc][0]=c0.x; gn[nc][1]=c0.y; gn[nc][2]=c0.z; gn[nc][3]=c0.w;
      gn[nc][4]=c1.x; gn[nc][5]=c1.y; gn[nc][6]=c1.z; gn[nc][7]=c1.w;
    }
    #pragma unroll
    for (int i = 0; i < 8; i++){
      int rp = i & 1;            // read hb[rp], write hb[rp^1]
      half8 a0v = *(const half8*)&hb[rp][0*32 + lq*8];
      half8 a1v = *(const half8*)&hb[rp][1*32 + lq*8];
      half8 a2v = *(const half8*)&hb[rp][2*32 + lq*8];
      half8 a3v = *(const half8*)&hb[rp][3*32 + lq*8];
      float4v cc[6], dd[6];
      #pragma unroll
      for (int q = 0; q < 6; q++){ cc[q] = (float4v){0,0,0,0}; dd[q] = (float4v){0,0,0,0}; }
      // two independent depth-2 chains per tile
      #pragma unroll
      for (int q = 0; q < 6; q++) cc[q] = __builtin_amdgcn_mfma_f32_16x16x32_f16(a0v, bfrag[q][0], cc[q], 0,0,0);
      #pragma unroll
      for (int q = 0; q < 6; q++) dd[q] = __builtin_amdgcn_mfma_f32_16x16x32_f16(a2v, bfrag[q][2], dd[q], 0,0,0);
      #pragma unroll
      for (int q = 0; q < 6; q++) cc[q] = __builtin_amdgcn_mfma_f32_16x16x32_f16(a1v, bfrag[q][1], cc[q], 0,0,0);
      #pragma unroll
      for (int q = 0; q < 6; q++) dd[q] = __builtin_amdgcn_mfma_f32_16x16x32_f16(a3v, bfrag[q][3], dd[q], 0,0,0);
      float ghr = (l & 16) ? (cc[1][0]+dd[1][0]) : (cc[0][0]+dd[0][0]);
      float ghz = (l & 16) ? (cc[3][0]+dd[3][0]) : (cc[2][0]+dd[2][0]);
      float ghn = (l & 16) ? (cc[5][0]+dd[5][0]) : (cc[4][0]+dd[4][0]);
      if (gate){
        float r = fsigmoid(gr[cb][i] + ghr);
        float z = fsigmoid(gz[cb][i] + ghz);
        float n = ftanh_(gn[cb][i] + r*(ghn + bn_));
        hval = (1.0f - z)*n + z*hval;
        hb[rp^1][j] = (_Float16)hval;
        ho[i] = (c*8 + i < len) ? hval : 0.0f;
      }
      __syncthreads();
    }
    if (gate){
      long ob = ((long)b*T_ + c*8)*H_ + j;
      #pragma unroll
      for (int i = 0; i < 8; i++) out[ob + (long)i*H_] = ho[i];
    }
    cb ^= 1;
  }
}

extern "C" void kernel_launch(void* const* d_in, const int* in_sizes, int n_in,
                              void* d_out, int out_size, void* d_ws, size_t ws_size,
                              hipStream_t stream) {
  char* base = (char*)d_ws;
  size_t off = 0;
  auto alloc = [&](size_t bytes)->void*{
    void* p = base + off; off = (off + bytes + 255) & ~(size_t)255; return p;
  };
  float* wcol = (float*)alloc((size_t)B_*D_*4);
  float* gi3  = (float*)alloc((size_t)B_*G_*T_*4);
  if (off > ws_size) return;

  const float* x   = (const float*)d_in[0];
  const float* mm  = (const float*)d_in[1];
  const float* vt  = (const float*)d_in[2];
  const int*   len = (const int*)d_in[4];
  const float* E   = (const float*)d_in[5];
  const float* wih = (const float*)d_in[6];
  const float* whh = (const float*)d_in[7];
  const float* bih = (const float*)d_in[8];
  const float* bhh = (const float*)d_in[9];

  adj_k<<<dim3(B_),dim3(256),0,stream>>>(mm, E, wcol);
  gi_k<<<dim3(256),dim3(512),0,stream>>>(x, mm, vt, E, wih, bih, bhh, wcol, gi3);
  gru_k<<<dim3(B_),dim3(256),0,stream>>>(gi3, whh, bhh, len, (float*)d_out);
}

// Round 9
// 265.487 us; speedup vs baseline: 2.0016x; 1.0470x over previous
//
#include <hip/hip_runtime.h>
#include <hip/hip_bf16.h>

#define B_ 32
#define T_ 256
#define D_ 64
#define H_ 128
#define G_ 384   // 3*H

typedef _Float16 half8 __attribute__((ext_vector_type(8)));
typedef _Float16 half4v __attribute__((ext_vector_type(4)));
typedef float float4v __attribute__((ext_vector_type(4)));

__device__ __forceinline__ float fsigmoid(float x){ return 1.0f/(1.0f+__expf(-x)); }
__device__ __forceinline__ float ftanh_(float x){ return 1.0f - 2.0f/(1.0f+__expf(2.0f*x)); }

// NOTE (R5-R7 post-mortem): inputs/outputs are f32 (reference is jnp.float32;
// R1's on-device {0,1}-mask detector confirmed). bf16 misread was the NaN bug.
//
// LDS-only barrier: the h ping-pong in LDS is the ONLY cross-wave dependency
// per step; gi prefetch loads / out stores are wave-private VGPR traffic whose
// completion the compiler tracks with its own vmcnt waits. Waiting lgkmcnt
// only skips the vmcnt(0) drain __syncthreads would force while prefetch and
// store batches are in flight (~600-1000 cyc per 8-step chunk). asm memory
// clobbers on BOTH sides pin LDS ops against the IntrNoMem s_barrier.
#define BAR() do{ asm volatile("s_waitcnt lgkmcnt(0)" ::: "memory"); \
                  __builtin_amdgcn_s_barrier(); \
                  asm volatile("" ::: "memory"); } while(0)

// wcol[b,j] = column sums of the row-normalized adjacency (R1 derivation):
// adj_raw[i,j] = p_i p_j sim_ij + I; rs_i = 1 + p_i*sum_j p_j sim_ij;
// wcol_j = p_j * sum_i p_i sim_ij / rs_i + 1/rs_j  (sim symmetric).
__global__ void __launch_bounds__(256) adj_k(const float* mm, const float* E,
                                             float* wcol){
  int b = blockIdx.x;
  int tid = threadIdx.x;
  int d = tid & 63, q = tid >> 6;
  __shared__ float spp[4][64];
  __shared__ float sp[64];
  __shared__ float sE[64*129];
  __shared__ float ssim[64*65];
  __shared__ float srs[64];
  float p = 0.0f;
  for (int t = q*64; t < q*64+64; t++) p += 1.0f - mm[(b*T_ + t)*D_ + d];
  spp[q][d] = p;
  for (int i = tid; i < D_*H_; i += 256){ int r = i >> 7, c = i & 127; sE[r*129+c] = E[i]; }
  __syncthreads();
  if (tid < 64) sp[tid] = (spp[0][tid]+spp[1][tid]+spp[2][tid]+spp[3][tid]) * (1.0f/T_);
  __syncthreads();
  float rowE[128];
  #pragma unroll
  for (int k = 0; k < 128; k++) rowE[k] = sE[d*129+k];
  for (int i = q*16; i < q*16+16; i++){
    float s = 0.0f;
    #pragma unroll
    for (int k = 0; k < 128; k++) s += rowE[k]*sE[i*129+k];
    ssim[d*65+i] = fmaxf(s, 0.0f);
  }
  __syncthreads();
  if (tid < 64){
    float rs = 0.0f;
    for (int j = 0; j < 64; j++) rs += sp[j]*ssim[tid*65+j];
    srs[tid] = fmaxf(sp[tid]*rs + 1.0f, 1e-6f);
  }
  __syncthreads();
  if (tid < 64){
    float s = 0.0f;
    for (int i = 0; i < 64; i++) s += sp[i]*ssim[tid*65+i]/srs[i];
    wcol[b*64 + tid] = sp[tid]*s + 1.0f/srs[tid];
  }
}

// gi_k v4 (f32 I/O): both phases MFMA GEMMs, 256 blocks (b x 8 t-chunks) x 512 thr.
// Phase A: vr[32t][128h] = (x*(1-mm)*wcol/64)[32t][64d] x E[64d][128h] + time-enc
// Phase B: gi[32t][384g] = vr x W_ih^T + (bih + bhh[r,z]); gi3 transposed [b][g][t].
#define AVP 72
#define VRP 136
__global__ void __launch_bounds__(512,1) gi_k(const float* x, const float* mm,
                                              const float* vt, const float* E,
                                              const float* wih, const float* bih,
                                              const float* bhh, const float* wcol,
                                              float* gi3){
  int bid = blockIdx.x;
  int b = bid >> 3, t0 = (bid & 7)*32;
  int tid = threadIdx.x;
  int w = tid >> 6, l = tid & 63;
  int lq = l >> 4, lm = l & 15;

  __shared__ __align__(16) _Float16 av[32*AVP];
  __shared__ __align__(16) _Float16 vrA[32*VRP];
  __shared__ float sVt[32];

  // stage av[t][d] = x*(1-mm)*wcol/64  (f32 in, f16 out)
  {
    int i = tid*4, t = i >> 6, d4 = i & 63;
    long src = (long)(b*T_ + t0 + t)*D_ + d4;
    float4 xv = *(const float4*)&x[src];
    float4 mv = *(const float4*)&mm[src];
    float4 wv = *(const float4*)&wcol[b*D_ + d4];
    half4v h;
    h[0]=(_Float16)(xv.x*(1.0f-mv.x)*wv.x*(1.0f/64));
    h[1]=(_Float16)(xv.y*(1.0f-mv.y)*wv.y*(1.0f/64));
    h[2]=(_Float16)(xv.z*(1.0f-mv.z)*wv.z*(1.0f/64));
    h[3]=(_Float16)(xv.w*(1.0f-mv.w)*wv.w*(1.0f/64));
    *(half4v*)&av[t*AVP + d4] = h;
  }
  if (tid < 32) sVt[tid] = vt[b*T_ + t0 + tid];
  // Phase A B-frags: B[k=d][n] = E[d][16w+n]  (one-time gather)
  half8 bE[2];
  #pragma unroll
  for (int kc = 0; kc < 2; kc++){
    half8 f;
    #pragma unroll
    for (int jj = 0; jj < 8; jj++)
      f[jj] = (_Float16)E[(kc*32 + lq*8 + jj)*H_ + 16*w + lm];
    bE[kc] = f;
  }
  __syncthreads();

  float4v accA[2] = {{0,0,0,0},{0,0,0,0}};
  #pragma unroll
  for (int kc = 0; kc < 2; kc++){
    #pragma unroll
    for (int mt = 0; mt < 2; mt++){
      half8 a = *(const half8*)&av[(mt*16+lm)*AVP + kc*32 + lq*8];
      accA[mt] = __builtin_amdgcn_mfma_f32_16x16x32_f16(a, bE[kc], accA[mt], 0,0,0);
    }
  }
  {
    int h = 16*w + lm;
    float fr = __expf(-(float)(h & 63) * 0.14391157f);   // ln(1e4)/64
    #pragma unroll
    for (int mt = 0; mt < 2; mt++){
      #pragma unroll
      for (int r = 0; r < 4; r++){
        int tl = mt*16 + lq*4 + r;
        float ang = sVt[tl] * fr;
        float e = (h < 64) ? __sinf(ang) : __cosf(ang);
        vrA[tl*VRP + h] = (_Float16)(accA[mt][r] + e);
      }
    }
  }
  __syncthreads();

  // Phase B: wave owns N-tiles 3w..3w+2
  half8 bW[3][4]; float biW[3];
  #pragma unroll
  for (int q = 0; q < 3; q++){
    int g = 16*(3*w + q) + lm;
    biW[q] = bih[g] + (g < 2*H_ ? bhh[g] : 0.0f);  // fold b_hh for r,z
    #pragma unroll
    for (int kc = 0; kc < 4; kc++){
      const float* src = &wih[(long)g*H_ + kc*32 + lq*8];
      float4 x0 = *(const float4*)src;
      float4 x1 = *(const float4*)(src+4);
      half8 f;
      f[0]=(_Float16)x0.x; f[1]=(_Float16)x0.y; f[2]=(_Float16)x0.z; f[3]=(_Float16)x0.w;
      f[4]=(_Float16)x1.x; f[5]=(_Float16)x1.y; f[6]=(_Float16)x1.z; f[7]=(_Float16)x1.w;
      bW[q][kc] = f;
    }
  }
  float4v cB[2][3];
  #pragma unroll
  for (int mt = 0; mt < 2; mt++)
    #pragma unroll
    for (int q = 0; q < 3; q++) cB[mt][q] = (float4v){0,0,0,0};
  #pragma unroll
  for (int kc = 0; kc < 4; kc++){
    #pragma unroll
    for (int mt = 0; mt < 2; mt++){
      half8 a = *(const half8*)&vrA[(mt*16+lm)*VRP + kc*32 + lq*8];
      #pragma unroll
      for (int q = 0; q < 3; q++)
        cB[mt][q] = __builtin_amdgcn_mfma_f32_16x16x32_f16(a, bW[q][kc], cB[mt][q], 0,0,0);
    }
  }
  #pragma unroll
  for (int mt = 0; mt < 2; mt++){
    #pragma unroll
    for (int q = 0; q < 3; q++){
      int g = 16*(3*w + q) + lm;
      int tb = t0 + mt*16 + lq*4;
      float4 v;
      v.x = cB[mt][q][0] + biW[q]; v.y = cB[mt][q][1] + biW[q];
      v.z = cB[mt][q][2] + biW[q]; v.w = cB[mt][q][3] + biW[q];
      *(float4*)&gi3[((long)(b*G_ + g))*T_ + tb] = v;
    }
  }
}

// Sequential GRU v9: R3's proven 4-wave layout (chained 4-deep MFMA accum —
// the R8 chain-split was a measured regression) + LDS-only BAR per step.
// Wave w owns 6 N-tiles (2 per gate part); gate lanes l<32 extract their
// triple via (l&16) select. h ping-pongs between two f16 LDS buffers; gi
// prefetched 8 steps/chunk from transposed gi3; out buffered per chunk.
__global__ void __launch_bounds__(256,1) gru_k(const float* gi3, const float* whh,
                                               const float* bhh, const int* lengths,
                                               float* out){
  int b = blockIdx.x;
  int tid = threadIdx.x;
  int w = tid >> 6, l = tid & 63;
  int lq = l >> 4, lm = l & 15;
  int len = lengths[b];
  bool gate = (l < 32);
  int j = 32*w + l;              // gate index when gate==true

  __shared__ __align__(16) _Float16 hb[2][H_];

  // B-frags: tile i base {32w, 32w+16} + part*128 ; B[k][n] = W_hh[nb+n][k]
  half8 bfrag[6][4];
  #pragma unroll
  for (int i = 0; i < 6; i++){
    int row = 32*w + (i>>1)*H_ + (i&1)*16 + lm;
    #pragma unroll
    for (int kc = 0; kc < 4; kc++){
      const float* src = &whh[(long)row*H_ + kc*32 + lq*8];
      float4 x0 = *(const float4*)src;
      float4 x1 = *(const float4*)(src+4);
      half8 f;
      f[0]=(_Float16)x0.x; f[1]=(_Float16)x0.y; f[2]=(_Float16)x0.z; f[3]=(_Float16)x0.w;
      f[4]=(_Float16)x1.x; f[5]=(_Float16)x1.y; f[6]=(_Float16)x1.z; f[7]=(_Float16)x1.w;
      bfrag[i][kc] = f;
    }
  }
  float bn_ = 0.0f;
  const float* pr = nullptr; const float* pz; const float* pn;
  if (gate){
    bn_ = bhh[2*H_ + j];
    pr = gi3 + ((long)b*G_ + j)*T_;
    pz = pr + (long)H_*T_;
    pn = pr + (long)2*H_*T_;
  }
  if (tid < H_){ hb[0][tid] = (_Float16)0.0f; hb[1][tid] = (_Float16)0.0f; }

  float gr[2][8], gz[2][8], gn[2][8];
  if (gate){
    float4 a0 = *(const float4*)(pr);  float4 a1 = *(const float4*)(pr+4);
    float4 b0 = *(const float4*)(pz);  float4 b1 = *(const float4*)(pz+4);
    float4 c0 = *(const float4*)(pn);  float4 c1 = *(const float4*)(pn+4);
    gr[0][0]=a0.x; gr[0][1]=a0.y; gr[0][2]=a0.z; gr[0][3]=a0.w;
    gr[0][4]=a1.x; gr[0][5]=a1.y; gr[0][6]=a1.z; gr[0][7]=a1.w;
    gz[0][0]=b0.x; gz[0][1]=b0.y; gz[0][2]=b0.z; gz[0][3]=b0.w;
    gz[0][4]=b1.x; gz[0][5]=b1.y; gz[0][6]=b1.z; gz[0][7]=b1.w;
    gn[0][0]=c0.x; gn[0][1]=c0.y; gn[0][2]=c0.z; gn[0][3]=c0.w;
    gn[0][4]=c1.x; gn[0][5]=c1.y; gn[0][6]=c1.z; gn[0][7]=c1.w;
  }
  __syncthreads();   // cold path: full barrier fine

  float hval = 0.0f;
  float ho[8];
  int cb = 0;
  for (int c = 0; c < 32; c++){
    if (gate && c+1 < 32){
      int nb2 = (c+1)*8;
      float4 a0 = *(const float4*)(pr+nb2);  float4 a1 = *(const float4*)(pr+nb2+4);
      float4 b0 = *(const float4*)(pz+nb2);  float4 b1 = *(const float4*)(pz+nb2+4);
      float4 c0 = *(const float4*)(pn+nb2);  float4 c1 = *(const float4*)(pn+nb2+4);
      int nc = cb^1;
      gr[nc][0]=a0.x; gr[nc][1]=a0.y; gr[nc][2]=a0.z; gr[nc][3]=a0.w;
      gr[nc][4]=a1.x; gr[nc][5]=a1.y; gr[nc][6]=a1.z; gr[nc][7]=a1.w;
      gz[nc][0]=b0.x; gz[nc][1]=b0.y; gz[nc][2]=b0.z; gz[nc][3]=b0.w;
      gz[nc][4]=b1.x; gz[nc][5]=b1.y; gz[nc][6]=b1.z; gz[nc][7]=b1.w;
      gn[nc][0]=c0.x; gn[nc][1]=c0.y; gn[nc][2]=c0.z; gn[nc][3]=c0.w;
      gn[nc][4]=c1.x; gn[nc][5]=c1.y; gn[nc][6]=c1.z; gn[nc][7]=c1.w;
    }
    #pragma unroll
    for (int i = 0; i < 8; i++){
      int rp = i & 1;            // read hb[rp], write hb[rp^1]
      half8 a0v = *(const half8*)&hb[rp][0*32 + lq*8];
      half8 a1v = *(const half8*)&hb[rp][1*32 + lq*8];
      half8 a2v = *(const half8*)&hb[rp][2*32 + lq*8];
      half8 a3v = *(const half8*)&hb[rp][3*32 + lq*8];
      float4v cc[6];
      #pragma unroll
      for (int q = 0; q < 6; q++) cc[q] = (float4v){0,0,0,0};
      #pragma unroll
      for (int q = 0; q < 6; q++) cc[q] = __builtin_amdgcn_mfma_f32_16x16x32_f16(a0v, bfrag[q][0], cc[q], 0,0,0);
      #pragma unroll
      for (int q = 0; q < 6; q++) cc[q] = __builtin_amdgcn_mfma_f32_16x16x32_f16(a1v, bfrag[q][1], cc[q], 0,0,0);
      #pragma unroll
      for (int q = 0; q < 6; q++) cc[q] = __builtin_amdgcn_mfma_f32_16x16x32_f16(a2v, bfrag[q][2], cc[q], 0,0,0);
      #pragma unroll
      for (int q = 0; q < 6; q++) cc[q] = __builtin_amdgcn_mfma_f32_16x16x32_f16(a3v, bfrag[q][3], cc[q], 0,0,0);
      float ghr = (l & 16) ? cc[1][0] : cc[0][0];
      float ghz = (l & 16) ? cc[3][0] : cc[2][0];
      float ghn = (l & 16) ? cc[5][0] : cc[4][0];
      if (gate){
        float r = fsigmoid(gr[cb][i] + ghr);
        float z = fsigmoid(gz[cb][i] + ghz);
        float n = ftanh_(gn[cb][i] + r*(ghn + bn_));
        hval = (1.0f - z)*n + z*hval;
        hb[rp^1][j] = (_Float16)hval;
        ho[i] = (c*8 + i < len) ? hval : 0.0f;
      }
      BAR();
    }
    if (gate){
      long ob = ((long)b*T_ + c*8)*H_ + j;
      #pragma unroll
      for (int i = 0; i < 8; i++) out[ob + (long)i*H_] = ho[i];
    }
    cb ^= 1;
  }
}

extern "C" void kernel_launch(void* const* d_in, const int* in_sizes, int n_in,
                              void* d_out, int out_size, void* d_ws, size_t ws_size,
                              hipStream_t stream) {
  char* base = (char*)d_ws;
  size_t off = 0;
  auto alloc = [&](size_t bytes)->void*{
    void* p = base + off; off = (off + bytes + 255) & ~(size_t)255; return p;
  };
  float* wcol = (float*)alloc((size_t)B_*D_*4);
  float* gi3  = (float*)alloc((size_t)B_*G_*T_*4);
  if (off > ws_size) return;

  const float* x   = (const float*)d_in[0];
  const float* mm  = (const float*)d_in[1];
  const float* vt  = (const float*)d_in[2];
  const int*   len = (const int*)d_in[4];
  const float* E   = (const float*)d_in[5];
  const float* wih = (const float*)d_in[6];
  const float* whh = (const float*)d_in[7];
  const float* bih = (const float*)d_in[8];
  const float* bhh = (const float*)d_in[9];

  adj_k<<<dim3(B_),dim3(256),0,stream>>>(mm, E, wcol);
  gi_k<<<dim3(256),dim3(512),0,stream>>>(x, mm, vt, E, wih, bih, bhh, wcol, gi3);
  gru_k<<<dim3(B_),dim3(256),0,stream>>>(gi3, whh, bhh, len, (float*)d_out);
}

// Round 10
// 256.862 us; speedup vs baseline: 2.0688x; 1.0336x over previous
//
#include <hip/hip_runtime.h>
#include <hip/hip_bf16.h>

#define B_ 32
#define T_ 256
#define D_ 64
#define H_ 128
#define G_ 384   // 3*H

typedef _Float16 half8 __attribute__((ext_vector_type(8)));
typedef _Float16 half4v __attribute__((ext_vector_type(4)));
typedef float float4v __attribute__((ext_vector_type(4)));

__device__ __forceinline__ float fsigmoid(float x){ return 1.0f/(1.0f+__expf(-x)); }
__device__ __forceinline__ float ftanh_(float x){ return 1.0f - 2.0f/(1.0f+__expf(2.0f*x)); }

// NOTE (R5-R7 post-mortem): inputs/outputs are f32 (reference is jnp.float32;
// R1's on-device {0,1}-mask detector confirmed). bf16 misread was the NaN bug.
//
// LDS-only barrier (R9: measured neutral vs __syncthreads, kept for the
// guaranteed absence of vmcnt drains). asm memory clobbers on BOTH sides pin
// LDS ops against the IntrNoMem s_barrier.
#define BAR() do{ asm volatile("s_waitcnt lgkmcnt(0)" ::: "memory"); \
                  __builtin_amdgcn_s_barrier(); \
                  asm volatile("" ::: "memory"); } while(0)

// wcol[b,j] = column sums of the row-normalized adjacency (R1 derivation):
// adj_raw[i,j] = p_i p_j sim_ij + I; rs_i = 1 + p_i*sum_j p_j sim_ij;
// wcol_j = p_j * sum_i p_i sim_ij / rs_i + 1/rs_j  (sim symmetric).
// sim loop stays SCALAR with pitch 129: odd pitch puts the 4 quads' divergent
// i-rows on different banks (16-apart) -> conflict-free broadcast; any
// b128-alignable (multiple-of-4) pitch would reintroduce 4-way conflicts.
__global__ void __launch_bounds__(256) adj_k(const float* mm, const float* E,
                                             float* wcol){
  int b = blockIdx.x;
  int tid = threadIdx.x;
  int d = tid & 63, q = tid >> 6;
  __shared__ float spp[4][64];
  __shared__ float sp[64];
  __shared__ float sE[64*129];
  __shared__ float ssim[64*65];
  __shared__ float srs[64];
  float p = 0.0f;
  for (int t = q*64; t < q*64+64; t++) p += 1.0f - mm[(b*T_ + t)*D_ + d];
  spp[q][d] = p;
  for (int i = tid; i < D_*H_; i += 256){ int r = i >> 7, c = i & 127; sE[r*129+c] = E[i]; }
  __syncthreads();
  if (tid < 64) sp[tid] = (spp[0][tid]+spp[1][tid]+spp[2][tid]+spp[3][tid]) * (1.0f/T_);
  __syncthreads();
  float rowE[128];
  #pragma unroll
  for (int k = 0; k < 128; k++) rowE[k] = sE[d*129+k];
  for (int i = q*16; i < q*16+16; i++){
    float s = 0.0f;
    #pragma unroll
    for (int k = 0; k < 128; k++) s += rowE[k]*sE[i*129+k];
    ssim[d*65+i] = fmaxf(s, 0.0f);
  }
  __syncthreads();
  if (tid < 64){
    float rs = 0.0f;
    for (int j = 0; j < 64; j++) rs += sp[j]*ssim[tid*65+j];
    srs[tid] = fmaxf(sp[tid]*rs + 1.0f, 1e-6f);
  }
  __syncthreads();
  if (tid < 64){
    float s = 0.0f;
    for (int i = 0; i < 64; i++) s += sp[i]*ssim[tid*65+i]/srs[i];
    wcol[b*64 + tid] = sp[tid]*s + 1.0f/srs[tid];
  }
}

// gi_k v5: gi3 now f16 (halves gi traffic); E staged into LDS f16 (pitch 132:
// quad stride 8*132 halves -> +2-bank offset pattern, 2-way max = free) so the
// Phase-A B-frag gather is LDS not scalar-global.
// Phase A: vr[32t][128h] = (x*(1-mm)*wcol/64)[32t][64d] x E[64d][128h] + time-enc
// Phase B: gi[32t][384g] = vr x W_ih^T + (bih + bhh[r,z]); gi3 transposed [b][g][t].
#define AVP 72
#define VRP 136
#define SEP 132
__global__ void __launch_bounds__(512,1) gi_k(const float* x, const float* mm,
                                              const float* vt, const float* E,
                                              const float* wih, const float* bih,
                                              const float* bhh, const float* wcol,
                                              _Float16* gi3){
  int bid = blockIdx.x;
  int b = bid >> 3, t0 = (bid & 7)*32;
  int tid = threadIdx.x;
  int w = tid >> 6, l = tid & 63;
  int lq = l >> 4, lm = l & 15;

  __shared__ __align__(16) _Float16 av[32*AVP];
  __shared__ __align__(16) _Float16 vrA[32*VRP];
  __shared__ __align__(16) _Float16 sEl[64*SEP];
  __shared__ float sVt[32];

  // stage av[t][d] = x*(1-mm)*wcol/64  (f32 in, f16 out)
  {
    int i = tid*4, t = i >> 6, d4 = i & 63;
    long src = (long)(b*T_ + t0 + t)*D_ + d4;
    float4 xv = *(const float4*)&x[src];
    float4 mv = *(const float4*)&mm[src];
    float4 wv = *(const float4*)&wcol[b*D_ + d4];
    half4v h;
    h[0]=(_Float16)(xv.x*(1.0f-mv.x)*wv.x*(1.0f/64));
    h[1]=(_Float16)(xv.y*(1.0f-mv.y)*wv.y*(1.0f/64));
    h[2]=(_Float16)(xv.z*(1.0f-mv.z)*wv.z*(1.0f/64));
    h[3]=(_Float16)(xv.w*(1.0f-mv.w)*wv.w*(1.0f/64));
    *(half4v*)&av[t*AVP + d4] = h;
  }
  // stage E -> LDS f16, coalesced (thread: 16 consecutive f32 of one row)
  {
    int r = tid >> 3, c0 = (tid & 7)*16;
    #pragma unroll
    for (int g = 0; g < 4; g++){
      float4 v = *(const float4*)&E[r*H_ + c0 + g*4];
      half4v h;
      h[0]=(_Float16)v.x; h[1]=(_Float16)v.y; h[2]=(_Float16)v.z; h[3]=(_Float16)v.w;
      *(half4v*)&sEl[r*SEP + c0 + g*4] = h;
    }
  }
  if (tid < 32) sVt[tid] = vt[b*T_ + t0 + tid];
  __syncthreads();

  // Phase A B-frags: B[k=d][n] = E[d][16w+n]  (gather from LDS)
  half8 bE[2];
  #pragma unroll
  for (int kc = 0; kc < 2; kc++){
    half8 f;
    #pragma unroll
    for (int jj = 0; jj < 8; jj++)
      f[jj] = sEl[(kc*32 + lq*8 + jj)*SEP + 16*w + lm];
    bE[kc] = f;
  }

  float4v accA[2] = {{0,0,0,0},{0,0,0,0}};
  #pragma unroll
  for (int kc = 0; kc < 2; kc++){
    #pragma unroll
    for (int mt = 0; mt < 2; mt++){
      half8 a = *(const half8*)&av[(mt*16+lm)*AVP + kc*32 + lq*8];
      accA[mt] = __builtin_amdgcn_mfma_f32_16x16x32_f16(a, bE[kc], accA[mt], 0,0,0);
    }
  }
  {
    int h = 16*w + lm;
    float fr = __expf(-(float)(h & 63) * 0.14391157f);   // ln(1e4)/64
    #pragma unroll
    for (int mt = 0; mt < 2; mt++){
      #pragma unroll
      for (int r = 0; r < 4; r++){
        int tl = mt*16 + lq*4 + r;
        float ang = sVt[tl] * fr;
        float e = (h < 64) ? __sinf(ang) : __cosf(ang);
        vrA[tl*VRP + h] = (_Float16)(accA[mt][r] + e);
      }
    }
  }
  __syncthreads();

  // Phase B: wave owns N-tiles 3w..3w+2
  half8 bW[3][4]; float biW[3];
  #pragma unroll
  for (int q = 0; q < 3; q++){
    int g = 16*(3*w + q) + lm;
    biW[q] = bih[g] + (g < 2*H_ ? bhh[g] : 0.0f);  // fold b_hh for r,z
    #pragma unroll
    for (int kc = 0; kc < 4; kc++){
      const float* src = &wih[(long)g*H_ + kc*32 + lq*8];
      float4 x0 = *(const float4*)src;
      float4 x1 = *(const float4*)(src+4);
      half8 f;
      f[0]=(_Float16)x0.x; f[1]=(_Float16)x0.y; f[2]=(_Float16)x0.z; f[3]=(_Float16)x0.w;
      f[4]=(_Float16)x1.x; f[5]=(_Float16)x1.y; f[6]=(_Float16)x1.z; f[7]=(_Float16)x1.w;
      bW[q][kc] = f;
    }
  }
  float4v cB[2][3];
  #pragma unroll
  for (int mt = 0; mt < 2; mt++)
    #pragma unroll
    for (int q = 0; q < 3; q++) cB[mt][q] = (float4v){0,0,0,0};
  #pragma unroll
  for (int kc = 0; kc < 4; kc++){
    #pragma unroll
    for (int mt = 0; mt < 2; mt++){
      half8 a = *(const half8*)&vrA[(mt*16+lm)*VRP + kc*32 + lq*8];
      #pragma unroll
      for (int q = 0; q < 3; q++)
        cB[mt][q] = __builtin_amdgcn_mfma_f32_16x16x32_f16(a, bW[q][kc], cB[mt][q], 0,0,0);
    }
  }
  #pragma unroll
  for (int mt = 0; mt < 2; mt++){
    #pragma unroll
    for (int q = 0; q < 3; q++){
      int g = 16*(3*w + q) + lm;
      int tb = t0 + mt*16 + lq*4;
      half4v hv;
      hv[0]=(_Float16)(cB[mt][q][0] + biW[q]); hv[1]=(_Float16)(cB[mt][q][1] + biW[q]);
      hv[2]=(_Float16)(cB[mt][q][2] + biW[q]); hv[3]=(_Float16)(cB[mt][q][3] + biW[q]);
      *(half4v*)&gi3[((long)(b*G_ + g))*T_ + tb] = hv;
    }
  }
}

// Sequential GRU v10: R9 structure (4 waves, chained 4-deep MFMA accum, one
// LDS-only BAR per step) with f16 gi3: one 16B load per gate stream per
// 8-step chunk (was two), converted to f32 at prefetch time so the consume
// path is identical to R9's.
__global__ void __launch_bounds__(256,1) gru_k(const _Float16* gi3, const float* whh,
                                               const float* bhh, const int* lengths,
                                               float* out){
  int b = blockIdx.x;
  int tid = threadIdx.x;
  int w = tid >> 6, l = tid & 63;
  int lq = l >> 4, lm = l & 15;
  int len = lengths[b];
  bool gate = (l < 32);
  int j = 32*w + l;              // gate index when gate==true

  __shared__ __align__(16) _Float16 hb[2][H_];

  // B-frags: tile i base {32w, 32w+16} + part*128 ; B[k][n] = W_hh[nb+n][k]
  half8 bfrag[6][4];
  #pragma unroll
  for (int i = 0; i < 6; i++){
    int row = 32*w + (i>>1)*H_ + (i&1)*16 + lm;
    #pragma unroll
    for (int kc = 0; kc < 4; kc++){
      const float* src = &whh[(long)row*H_ + kc*32 + lq*8];
      float4 x0 = *(const float4*)src;
      float4 x1 = *(const float4*)(src+4);
      half8 f;
      f[0]=(_Float16)x0.x; f[1]=(_Float16)x0.y; f[2]=(_Float16)x0.z; f[3]=(_Float16)x0.w;
      f[4]=(_Float16)x1.x; f[5]=(_Float16)x1.y; f[6]=(_Float16)x1.z; f[7]=(_Float16)x1.w;
      bfrag[i][kc] = f;
    }
  }
  float bn_ = 0.0f;
  const _Float16* pr = nullptr; const _Float16* pz; const _Float16* pn;
  if (gate){
    bn_ = bhh[2*H_ + j];
    pr = gi3 + ((long)b*G_ + j)*T_;
    pz = pr + (long)H_*T_;
    pn = pr + (long)2*H_*T_;
  }
  if (tid < H_){ hb[0][tid] = (_Float16)0.0f; hb[1][tid] = (_Float16)0.0f; }

  float gr[2][8], gz[2][8], gn[2][8];
  if (gate){
    half8 a = *(const half8*)(pr);
    half8 bv = *(const half8*)(pz);
    half8 cv = *(const half8*)(pn);
    #pragma unroll
    for (int i = 0; i < 8; i++){ gr[0][i]=(float)a[i]; gz[0][i]=(float)bv[i]; gn[0][i]=(float)cv[i]; }
  }
  __syncthreads();   // cold path: full barrier fine

  float hval = 0.0f;
  float ho[8];
  int cb = 0;
  for (int c = 0; c < 32; c++){
    if (gate && c+1 < 32){
      int nb2 = (c+1)*8;
      half8 a = *(const half8*)(pr+nb2);
      half8 bv = *(const half8*)(pz+nb2);
      half8 cv = *(const half8*)(pn+nb2);
      int nc = cb^1;
      #pragma unroll
      for (int i = 0; i < 8; i++){ gr[nc][i]=(float)a[i]; gz[nc][i]=(float)bv[i]; gn[nc][i]=(float)cv[i]; }
    }
    #pragma unroll
    for (int i = 0; i < 8; i++){
      int rp = i & 1;            // read hb[rp], write hb[rp^1]
      half8 a0v = *(const half8*)&hb[rp][0*32 + lq*8];
      half8 a1v = *(const half8*)&hb[rp][1*32 + lq*8];
      half8 a2v = *(const half8*)&hb[rp][2*32 + lq*8];
      half8 a3v = *(const half8*)&hb[rp][3*32 + lq*8];
      float4v cc[6];
      #pragma unroll
      for (int q = 0; q < 6; q++) cc[q] = (float4v){0,0,0,0};
      #pragma unroll
      for (int q = 0; q < 6; q++) cc[q] = __builtin_amdgcn_mfma_f32_16x16x32_f16(a0v, bfrag[q][0], cc[q], 0,0,0);
      #pragma unroll
      for (int q = 0; q < 6; q++) cc[q] = __builtin_amdgcn_mfma_f32_16x16x32_f16(a1v, bfrag[q][1], cc[q], 0,0,0);
      #pragma unroll
      for (int q = 0; q < 6; q++) cc[q] = __builtin_amdgcn_mfma_f32_16x16x32_f16(a2v, bfrag[q][2], cc[q], 0,0,0);
      #pragma unroll
      for (int q = 0; q < 6; q++) cc[q] = __builtin_amdgcn_mfma_f32_16x16x32_f16(a3v, bfrag[q][3], cc[q], 0,0,0);
      float ghr = (l & 16) ? cc[1][0] : cc[0][0];
      float ghz = (l & 16) ? cc[3][0] : cc[2][0];
      float ghn = (l & 16) ? cc[5][0] : cc[4][0];
      if (gate){
        float r = fsigmoid(gr[cb][i] + ghr);
        float z = fsigmoid(gz[cb][i] + ghz);
        float n = ftanh_(gn[cb][i] + r*(ghn + bn_));
        hval = (1.0f - z)*n + z*hval;
        hb[rp^1][j] = (_Float16)hval;
        ho[i] = (c*8 + i < len) ? hval : 0.0f;
      }
      BAR();
    }
    if (gate){
      long ob = ((long)b*T_ + c*8)*H_ + j;
      #pragma unroll
      for (int i = 0; i < 8; i++) out[ob + (long)i*H_] = ho[i];
    }
    cb ^= 1;
  }
}

extern "C" void kernel_launch(void* const* d_in, const int* in_sizes, int n_in,
                              void* d_out, int out_size, void* d_ws, size_t ws_size,
                              hipStream_t stream) {
  char* base = (char*)d_ws;
  size_t off = 0;
  auto alloc = [&](size_t bytes)->void*{
    void* p = base + off; off = (off + bytes + 255) & ~(size_t)255; return p;
  };
  float*     wcol = (float*)alloc((size_t)B_*D_*4);
  _Float16*  gi3  = (_Float16*)alloc((size_t)B_*G_*T_*2);
  if (off > ws_size) return;

  const float* x   = (const float*)d_in[0];
  const float* mm  = (const float*)d_in[1];
  const float* vt  = (const float*)d_in[2];
  const int*   len = (const int*)d_in[4];
  const float* E   = (const float*)d_in[5];
  const float* wih = (const float*)d_in[6];
  const float* whh = (const float*)d_in[7];
  const float* bih = (const float*)d_in[8];
  const float* bhh = (const float*)d_in[9];

  adj_k<<<dim3(B_),dim3(256),0,stream>>>(mm, E, wcol);
  gi_k<<<dim3(256),dim3(512),0,stream>>>(x, mm, vt, E, wih, bih, bhh, wcol, gi3);
  gru_k<<<dim3(B_),dim3(256),0,stream>>>(gi3, whh, bhh, len, (float*)d_out);
}